// Round 8
// baseline (4084.154 us; speedup 1.0000x reference)
//
#include <hip/hip_runtime.h>
#include <hip/hip_bf16.h>
#include <math.h>

typedef unsigned short u16;
typedef unsigned int   u32;
typedef __attribute__((ext_vector_type(8))) short short8;   // 8 bf16 = 4 VGPRs
typedef __attribute__((ext_vector_type(4))) float f32x4;

// ---- model dims ----
#define BSZ   64
#define TT    96
#define CCH   16
#define INDIM 16
#define HD    256
#define NHEAD 8
#define DHEAD 32
#define NCLS  4
#define LSEQ  100      // TT + NCLS
#define NLAY  4
#define EPSV  1e-5f
#define BSEQ  (BSZ*CCH)        // 1024 sequences
#define MTOK  (BSEQ*LSEQ)      // 102400 tokens

#if __has_builtin(__builtin_amdgcn_exp2f)
#define EXP2F __builtin_amdgcn_exp2f
#else
#define EXP2F exp2f
#endif

__device__ __forceinline__ float bf2f(u16 x){ return __uint_as_float(((u32)x)<<16); }
__device__ __forceinline__ u16 f2bf(float f){
    u32 u = __float_as_uint(f);
    u32 r = (u + 0x7fffu + ((u>>16)&1u)) >> 16;
    return (u16)r;
}
__device__ __forceinline__ float lo16(u32 r){ return __uint_as_float(r<<16); }
__device__ __forceinline__ float hi16(u32 r){ return __uint_as_float(r&0xffff0000u); }

// HW packed f32->bf16 (RNE), 1 instr per 2 elements
__device__ __forceinline__ u32 cvtpk(float lo, float hi){
    u32 r;
    asm("v_cvt_pk_bf16_f32 %0, %1, %2" : "=v"(r) : "v"(lo), "v"(hi));
    return r;
}

// ---------------- f32 -> bf16 bulk convert ----------------
__global__ __launch_bounds__(256)
void k_cvt(const float* __restrict__ src, u16* __restrict__ dst, int n)
{
    for (int i = blockIdx.x*256 + threadIdx.x; i < n; i += gridDim.x*256)
        dst[i] = f2bf(src[i]);
}

// ---------------- embed ----------------
__global__ __launch_bounds__(256)
void k_embed(const float* __restrict__ x, const float* __restrict__ Wfc,
             const float* __restrict__ bfc, const float* __restrict__ cls,
             const float* __restrict__ pos, u16* __restrict__ h)
{
    int s = blockIdx.x;                // 0..1023 = n*16 + c
    int n = s >> 4, c = s & 15;
    int hc = threadIdx.x;
    float wr[INDIM];
    #pragma unroll
    for (int i=0;i<INDIM;i++) wr[i] = Wfc[hc*INDIM + i];
    float bb = bfc[hc];
    for (int l=0; l<TT; l++){
        const float* xr = x + (size_t)((n*TT + l)*CCH + c)*INDIM;
        float acc = bb;
        #pragma unroll
        for (int i=0;i<INDIM;i++) acc += xr[i]*wr[i];
        acc += pos[(size_t)(l*CCH + c)*HD + hc];
        h[((size_t)s*LSEQ + l)*HD + hc] = f2bf(acc);
    }
    #pragma unroll
    for (int l=TT; l<LSEQ; l++){
        float v = cls[(size_t)((l-TT)*CCH + c)*HD + hc]
                + pos[(size_t)(l*CCH + c)*HD + hc];
        h[((size_t)s*LSEQ + l)*HD + hc] = f2bf(v);
    }
}

// ---------------- graph constructor ----------------
__global__ __launch_bounds__(256)
void k_graph_m(const float* __restrict__ emb, const float* __restrict__ Wl,
               const float* __restrict__ bl, float* __restrict__ m)
{
    int r = blockIdx.x, o = threadIdx.x;
    __shared__ float e[HD];
    e[o] = emb[r*HD + o];
    __syncthreads();
    const float* w = Wl + (size_t)o*HD;
    float acc = bl[o];
    for (int k=0;k<HD;k++) acc += e[k]*w[k];
    m[r*HD + o] = tanhf(acc);
}

__global__ __launch_bounds__(256)
void k_graph_a(const float* __restrict__ m1, const float* __restrict__ m2,
               float* __restrict__ a)
{
    int t = threadIdx.x; int v = t >> 4, w = t & 15;
    __shared__ float adj[16][17];
    float s1=0.f, s2=0.f;
    for (int k=0;k<HD;k++){
        s1 += m1[v*HD+k]*m2[w*HD+k];
        s2 += m2[v*HD+k]*m1[w*HD+k];
    }
    float g = tanhf(s1 - s2); g = g > 0.f ? g : 0.f;
    adj[v][w] = g + (v==w ? 1.f : 0.f);
    __syncthreads();
    float rs = 0.f;
    #pragma unroll
    for (int j=0;j<16;j++) rs += adj[v][j];
    a[t] = adj[v][w] / rs;
}

// ---- MFMA GEMM: direct global->register fragments, no LDS staging, no K-loop barriers.
// W rows per-wave-unique (L2 serves inter-block reuse); A shared 2x (L1/L2 dedupes).
// Hand-pipelined 1 K-step ahead with two statically-indexed register sets.
// N-major grid + XCD swizzle; epilogue stages C tile in LDS for full-line stores.
__global__ __launch_bounds__(256)
void k_gemmA(const u16* __restrict__ A, int lda,
             const u16* __restrict__ W, const float* __restrict__ bias,
             u16* __restrict__ C, int ldc, int K, int relu, int scat)
{
    __shared__ u16 smem[16384];            // 32 KB: epilogue C-tile only
    int t = threadIdx.x;
    int lane = t & 63, w = t >> 6;
    int wm = (w & 1)*64, wn = (w >> 1)*64;
    int fr = lane & 15, quad = lane >> 4;

    // XCD-aware tile remap (bijective; all grids here are %8==0)
    int nwg = gridDim.x * gridDim.y;
    int bid = blockIdx.y * gridDim.x + blockIdx.x;
    int tile = bid;
    if (!(nwg & 7)){
        int cpx = nwg >> 3;
        tile = (bid & 7)*cpx + (bid >> 3);
    }
    int bx = tile % gridDim.x, by = tile / gridDim.x;
    size_t mb = (size_t)by * 128;
    int nb = bx * 128;

    const u16* Ab[4]; const u16* Wb[4];
    #pragma unroll
    for (int i=0;i<4;i++){
        Ab[i] = A + (mb + wm + i*16 + fr)*(size_t)lda + quad*8;
        Wb[i] = W + (size_t)(nb + wn + i*16 + fr)*K + quad*8;
    }

    f32x4 acc[4][4] = {};
    short8 fa0[2][4], fa1[2][4], fb0[2][4], fb1[2][4];

#define GLOADA(S, k0) { \
    _Pragma("unroll") \
    for (int i=0;i<4;i++){ \
        fa0[S][i] = *(const short8*)(Ab[i] + (k0)); \
        fa1[S][i] = *(const short8*)(Ab[i] + (k0) + 32); \
        fb0[S][i] = *(const short8*)(Wb[i] + (k0)); \
        fb1[S][i] = *(const short8*)(Wb[i] + (k0) + 32); \
    } }

#define GMFMAA(S) { \
    _Pragma("unroll") \
    for (int mt=0; mt<4; mt++) \
        _Pragma("unroll") \
        for (int nt=0; nt<4; nt++){ \
            acc[mt][nt] = __builtin_amdgcn_mfma_f32_16x16x32_bf16(fa0[S][mt], fb0[S][nt], acc[mt][nt], 0,0,0); \
            acc[mt][nt] = __builtin_amdgcn_mfma_f32_16x16x32_bf16(fa1[S][mt], fb1[S][nt], acc[mt][nt], 0,0,0); \
        } }

    const int nst = K >> 6;
    GLOADA(0, 0)
    int ts = 0;
    for (;;){
        if (ts + 1 < nst) GLOADA(1, (ts+1) << 6)
        GMFMAA(0)
        if (++ts == nst) break;
        if (ts + 1 < nst) GLOADA(0, (ts+1) << 6)
        GMFMAA(1)
        if (++ts == nst) break;
    }
#undef GLOADA
#undef GMFMAA

    // ---- epilogue: bias(+relu) -> LDS tile -> coalesced dwordx4 stores ----
    float bb4[4];
    #pragma unroll
    for (int nt=0; nt<4; nt++) bb4[nt] = bias[nb + wn + nt*16 + fr];
    u16* Ct = smem;                        // 128x128 u16
    #pragma unroll
    for (int mt=0; mt<4; mt++){
        int rw = wm + mt*16 + quad*4;
        #pragma unroll
        for (int nt=0; nt<4; nt++){
            int col = wn + nt*16 + fr;
            float v0 = acc[mt][nt][0] + bb4[nt];
            float v1 = acc[mt][nt][1] + bb4[nt];
            float v2 = acc[mt][nt][2] + bb4[nt];
            float v3 = acc[mt][nt][3] + bb4[nt];
            if (relu){
                v0 = v0 > 0.f ? v0 : 0.f;  v1 = v1 > 0.f ? v1 : 0.f;
                v2 = v2 > 0.f ? v2 : 0.f;  v3 = v3 > 0.f ? v3 : 0.f;
            }
            u32 p01 = cvtpk(v0, v1), p23 = cvtpk(v2, v3);
            Ct[(rw+0)*128 + col] = (u16)p01;
            Ct[(rw+1)*128 + col] = (u16)(p01 >> 16);
            Ct[(rw+2)*128 + col] = (u16)p23;
            Ct[(rw+3)*128 + col] = (u16)(p23 >> 16);
        }
    }
    __syncthreads();
    #pragma unroll
    for (int it=0; it<8; ++it){
        int row = it*16 + (t>>4);
        int seg = t & 15;
        size_t rg = mb + row;
        if (scat) rg = (rg >> 2)*LSEQ + TT + (rg & 3);
        *(short8*)&C[rg*(size_t)ldc + nb + seg*8] = *(const short8*)&Ct[row*128 + seg*8];
    }
}

// ------- MFMA GEMM (N=256) + bias + residual + LayerNorm fused, in-place h -------
// Direct global->register K-loop (no LDS staging / barriers), same as k_gemmA.
// Wave w owns 64x64 sub-tile (cols w*64..). LN epilogue via LDS cross-wave reduction.
__global__ __launch_bounds__(256)
void k_gemmC(const u16* __restrict__ A, int lda, int K,
             const u16* __restrict__ W, const float* __restrict__ bias,
             u16* __restrict__ h, const float* __restrict__ gam,
             const float* __restrict__ bet, size_t row0)
{
    __shared__ u16 smem[17408];            // red 1KB | red2 1KB | Ct 32KB
    int t = threadIdx.x;
    int lane = t & 63, w = t >> 6;
    int fr = lane & 15, quad = lane >> 4;
    size_t mb = (size_t)blockIdx.x * 64;

    const u16* Ab[4]; const u16* Wb[4];
    #pragma unroll
    for (int i=0;i<4;i++){
        Ab[i] = A + (mb + i*16 + fr)*(size_t)lda + quad*8;
        Wb[i] = W + (size_t)(w*64 + i*16 + fr)*K + quad*8;
    }

    f32x4 acc[4][4] = {};
    short8 fa0[2][4], fa1[2][4], fb0[2][4], fb1[2][4];

#define GLOADC(S, k0) { \
    _Pragma("unroll") \
    for (int i=0;i<4;i++){ \
        fa0[S][i] = *(const short8*)(Ab[i] + (k0)); \
        fa1[S][i] = *(const short8*)(Ab[i] + (k0) + 32); \
        fb0[S][i] = *(const short8*)(Wb[i] + (k0)); \
        fb1[S][i] = *(const short8*)(Wb[i] + (k0) + 32); \
    } }

#define GMFMAC(S) { \
    _Pragma("unroll") \
    for (int mt=0; mt<4; mt++) \
        _Pragma("unroll") \
        for (int nt=0; nt<4; nt++){ \
            acc[mt][nt] = __builtin_amdgcn_mfma_f32_16x16x32_bf16(fa0[S][mt], fb0[S][nt], acc[mt][nt], 0,0,0); \
            acc[mt][nt] = __builtin_amdgcn_mfma_f32_16x16x32_bf16(fa1[S][mt], fb1[S][nt], acc[mt][nt], 0,0,0); \
        } }

    const int nst = K >> 6;
    GLOADC(0, 0)
    int ts = 0;
    for (;;){
        if (ts + 1 < nst) GLOADC(1, (ts+1) << 6)
        GMFMAC(0)
        if (++ts == nst) break;
        if (ts + 1 < nst) GLOADC(0, (ts+1) << 6)
        GMFMAC(1)
        if (++ts == nst) break;
    }
#undef GLOADC
#undef GMFMAC

    // ---- epilogue: v = acc + bias + residual ----
    float bb4[4], gg[4], be[4];
    #pragma unroll
    for (int nt=0; nt<4; nt++){
        int col = w*64 + nt*16 + fr;
        bb4[nt] = bias[col]; gg[nt] = gam[col]; be[nt] = bet[col];
    }
    #pragma unroll
    for (int mt=0; mt<4; mt++){
        #pragma unroll
        for (int r=0; r<4; r++){
            size_t row = row0 + mb + mt*16 + quad*4 + r;
            #pragma unroll
            for (int nt=0; nt<4; nt++)
                acc[mt][nt][r] += bb4[nt] + bf2f(h[row*HD + w*64 + nt*16 + fr]);
        }
    }
    float* red  = (float*)smem;            // 256 f32 @ byte 0
    float* red2 = (float*)(smem + 512);    // 256 f32 @ byte 1024
    float ps[4][4];
    #pragma unroll
    for (int mt=0; mt<4; mt++)
        #pragma unroll
        for (int r=0; r<4; r++){
            float s = acc[mt][0][r] + acc[mt][1][r] + acc[mt][2][r] + acc[mt][3][r];
            s += __shfl_xor(s,1,64); s += __shfl_xor(s,2,64);
            s += __shfl_xor(s,4,64); s += __shfl_xor(s,8,64);
            ps[mt][r] = s;
        }
    if (fr == 0){
        #pragma unroll
        for (int mt=0; mt<4; mt++)
            #pragma unroll
            for (int r=0; r<4; r++)
                red[w*64 + mt*16 + quad*4 + r] = ps[mt][r];
    }
    __syncthreads();
    float mean[4][4];
    #pragma unroll
    for (int mt=0; mt<4; mt++)
        #pragma unroll
        for (int r=0; r<4; r++){
            int rl = mt*16 + quad*4 + r;
            mean[mt][r] = (red[rl] + red[64+rl] + red[128+rl] + red[192+rl]) * (1.f/256.f);
            float s = 0.f;
            #pragma unroll
            for (int nt=0; nt<4; nt++){ float d = acc[mt][nt][r] - mean[mt][r]; s += d*d; }
            s += __shfl_xor(s,1,64); s += __shfl_xor(s,2,64);
            s += __shfl_xor(s,4,64); s += __shfl_xor(s,8,64);
            ps[mt][r] = s;
        }
    if (fr == 0){
        #pragma unroll
        for (int mt=0; mt<4; mt++)
            #pragma unroll
            for (int r=0; r<4; r++)
                red2[w*64 + mt*16 + quad*4 + r] = ps[mt][r];
    }
    __syncthreads();
    // ---- normalize -> LDS tile -> coalesced stores ----
    u16* Ct = smem + 1024;                 // 64x256 u16 @ byte 2048
    #pragma unroll
    for (int mt=0; mt<4; mt++)
        #pragma unroll
        for (int r=0; r<4; r++){
            int rl = mt*16 + quad*4 + r;
            float inv = rsqrtf((red2[rl] + red2[64+rl] + red2[128+rl] + red2[192+rl])
                               * (1.f/256.f) + EPSV);
            float o0 = (acc[mt][0][r] - mean[mt][r]) * inv * gg[0] + be[0];
            float o1 = (acc[mt][1][r] - mean[mt][r]) * inv * gg[1] + be[1];
            float o2 = (acc[mt][2][r] - mean[mt][r]) * inv * gg[2] + be[2];
            float o3 = (acc[mt][3][r] - mean[mt][r]) * inv * gg[3] + be[3];
            u32 p01 = cvtpk(o0, o1), p23 = cvtpk(o2, o3);
            Ct[rl*256 + w*64 +  0 + fr] = (u16)p01;
            Ct[rl*256 + w*64 + 16 + fr] = (u16)(p01 >> 16);
            Ct[rl*256 + w*64 + 32 + fr] = (u16)p23;
            Ct[rl*256 + w*64 + 48 + fr] = (u16)(p23 >> 16);
        }
    __syncthreads();
    #pragma unroll
    for (int it=0; it<8; ++it){
        int row = it*8 + (t>>5);
        int seg = t & 31;
        *(short8*)&h[(row0 + mb + row)*HD + seg*8] = *(const short8*)&Ct[row*256 + seg*8];
    }
}

// ---------------- MFMA attention with causal tile-skipping ----------------
// (unchanged from r7)
#define KS_STR 40
#define VT_STR 136
__global__ __launch_bounds__(256)
void k_attn(u16* __restrict__ qkv)
{
    __shared__ u16 smem[17664];   // stage: Ks 2x4480 @0 | Vt 2x4352 @8960
                                  // strips: Ph 4x2048 @0 (over Ks) | Pv 4x2048 @8960 (over Vt)
    int t = threadIdx.x;
    int w = t >> 6, lane = t & 63;
    int fr = lane & 15, quad = lane >> 4;
    int p = t >> 7, t2 = t & 127;
    u16* Ks = smem + p*4480;
    u16* Vt = smem + 8960 + p*4352;

    {
        int gp = blockIdx.x*2 + p;
        size_t base = (size_t)(gp >> 3)*LSEQ*768 + (gp & 7)*32;
        for (int idx = t2; idx < 1792; idx += 128){
            int key = idx >> 4, d2 = (idx & 15) << 1;
            u32 kv = (key < LSEQ) ? *(const u32*)&qkv[base + (size_t)key*768 + 256 + d2] : 0u;
            *(u32*)&Ks[key*KS_STR + d2] = kv;
        }
        // key-major V transpose staging: lanes stride-1 in key -> conflict-free writes
        for (int idx = t2; idx < 2048; idx += 128){
            int key = idx & 127, d2 = (idx >> 7) << 1;
            u32 vv = (key < LSEQ) ? *(const u32*)&qkv[base + (size_t)key*768 + 512 + d2] : 0u;
            Vt[ d2   *VT_STR + key] = (u16)(vv & 0xffffu);
            Vt[(d2+1)*VT_STR + key] = (u16)(vv >> 16);
        }
    }
    __syncthreads();

    int wp = w >> 1;
    int gp = blockIdx.x*2 + wp;
    size_t base = (size_t)(gp >> 3)*LSEQ*768 + (gp & 7)*32;
    u16* Ksw = smem + wp*4480;
    u16* Vtw = smem + 8960 + wp*4352;

    short8 kf[7];
    #pragma unroll
    for (int nt=0; nt<7; nt++)
        kf[nt] = *(const short8*)&Ksw[(nt*16 + fr)*KS_STR + quad*8];
    short8 vfr[4][2];
    #pragma unroll
    for (int ks=0; ks<4; ks++)
        #pragma unroll
        for (int nt=0; nt<2; nt++)
            vfr[ks][nt] = *(const short8*)&Vtw[(nt*16 + fr)*VT_STR + ks*32 + quad*8];

    const int smask = (w & 1) ? 0x34 : 0x4B;   // strips {2,4,5} / {0,1,3,6}
    // prefetch q fragments for this wave's strips (before any output store can alias)
    short8 qfs[7];
    #pragma unroll
    for (int st=0; st<7; ++st){
        if (!((smask >> st) & 1)) continue;
        int q = st*16 + fr;
        short8 z = {};
        qfs[st] = (q < LSEQ) ? *(const short8*)&qkv[base + (size_t)q*768 + quad*8] : z;
    }
    __syncthreads();   // all waves done reading Ks/Vt before Ph/Pv overlay reuse

    u16* Ph = smem + w*2048;           // P_hi over dead Ks region
    u16* Pv = smem + 8960 + w*2048;    // P_lo over dead Vt region

    const float cs = 0.17677669529663687f * 1.4426950408889634f;  // (1/sqrt32)*log2(e)
    #pragma unroll
    for (int st = 0; st < 7; ++st){
        if (!((smask >> st) & 1)) continue;
        const int ntile = (st == 6) ? 7 : (st + 1);
        const int nks   = (st == 6) ? 4 : (st/2 + 1);
        f32x4 S[7];
        #pragma unroll
        for (int nt=0; nt<7; nt++){
            if (nt >= ntile) continue;
            f32x4 z = {};
            S[nt] = __builtin_amdgcn_mfma_f32_16x16x32_bf16(qfs[st], kf[nt], z, 0,0,0);
        }
        // scale (in log2 domain); mask ONLY the last tile (full tiles causal-valid)
        float mx[4] = {-1e30f,-1e30f,-1e30f,-1e30f};
        #pragma unroll
        for (int nt=0;nt<7;nt++){
            if (nt >= ntile) continue;
            #pragma unroll
            for (int r=0;r<4;r++){
                float s = S[nt][r]*cs;
                if (nt == ntile-1){
                    int qr = st*16 + quad*4 + r;
                    int jmax = (qr < TT) ? qr : (LSEQ-1);
                    s = ((nt*16 + fr) <= jmax) ? s : -1e30f;
                }
                S[nt][r] = s;
                mx[r] = fmaxf(mx[r], s);
            }
        }
        #pragma unroll
        for (int r=0;r<4;r++){
            #pragma unroll
            for (int m=1;m<16;m<<=1) mx[r] = fmaxf(mx[r], __shfl_xor(mx[r], m, 64));
        }
        float l4[4] = {0.f,0.f,0.f,0.f};
        #pragma unroll
        for (int r=0;r<4;r++){
            #pragma unroll
            for (int nt=0;nt<7;nt++){
                if (nt >= ntile) continue;
                float pv = EXP2F(S[nt][r] - mx[r]);
                S[nt][r] = pv;
                l4[r] += pv;
            }
        }
        #pragma unroll
        for (int r=0;r<4;r++){
            #pragma unroll
            for (int m=1;m<16;m<<=1) l4[r] += __shfl_xor(l4[r], m, 64);
        }
        // WAR fence: previous strip's Ph/Pv reads must complete before overwrite
        asm volatile("s_waitcnt lgkmcnt(0)" ::: "memory");
        // write P_hi + P_lo via packed cvt; panel layout [ks][16 rows][32 k], XOR swizzle
        #pragma unroll
        for (int nt=0;nt<7;nt++){
            if (nt >= ntile) continue;
            u32 h01 = cvtpk(S[nt][0], S[nt][1]);
            u32 h23 = cvtpk(S[nt][2], S[nt][3]);
            float l0 = S[nt][0] - lo16(h01);
            float l1 = S[nt][1] - hi16(h01);
            float l2 = S[nt][2] - lo16(h23);
            float l3 = S[nt][3] - hi16(h23);
            u32 g01 = cvtpk(l0, l1);
            u32 g23 = cvtpk(l2, l3);
            u16 hv[4] = {(u16)h01, (u16)(h01>>16), (u16)h23, (u16)(h23>>16)};
            u16 lv[4] = {(u16)g01, (u16)(g01>>16), (u16)g23, (u16)(g23>>16)};
            #pragma unroll
            for (int r=0;r<4;r++){
                int row = quad*4 + r;
                int a = (nt>>1)*512 + row*32 + ((((nt&1)<<4) + fr) ^ (((row>>1)&3)<<3));
                Ph[a] = hv[r];
                Pv[a] = lv[r];
            }
        }
        if (ntile*16 < nks*32){
            #pragma unroll
            for (int r=0;r<4;r++){
                int row = quad*4 + r;
                int a = (ntile>>1)*512 + row*32 + ((((ntile&1)<<4) + fr) ^ (((row>>1)&3)<<3));
                Ph[a] = 0;
                Pv[a] = 0;
            }
        }
        asm volatile("s_waitcnt lgkmcnt(0)" ::: "memory");
        f32x4 D[2] = {};
        #pragma unroll
        for (int ks=0; ks<4; ks++){
            if (ks >= nks) continue;
            int a = ks*512 + fr*32 + ((quad ^ ((fr>>1)&3)) << 3);
            short8 ph = *(const short8*)&Ph[a];
            short8 pl = *(const short8*)&Pv[a];
            #pragma unroll
            for (int nt=0; nt<2; nt++){
                D[nt] = __builtin_amdgcn_mfma_f32_16x16x32_bf16(ph, vfr[ks][nt], D[nt], 0,0,0);
                D[nt] = __builtin_amdgcn_mfma_f32_16x16x32_bf16(pl, vfr[ks][nt], D[nt], 0,0,0);
            }
        }
        #pragma unroll
        for (int r=0;r<4;r++){
            int qr = st*16 + quad*4 + r;
            if (qr < LSEQ){
                float inv = 1.f / l4[r];
                u32 o = cvtpk(D[0][r]*inv, D[1][r]*inv);
                qkv[base + (size_t)qr*768 +      fr] = (u16)o;
                qkv[base + (size_t)qr*768 + 16 + fr] = (u16)(o >> 16);
            }
        }
        // no trailing drain: next strip's WAR fence orders LDS; global rows disjoint
    }
}

// ---------------- mixprop prep ----------------
__global__ __launch_bounds__(256)
void k_mixprep(const u16* __restrict__ h, const float* __restrict__ a,
               u16* __restrict__ amid)
{
    int n = blockIdx.x >> 2, tt = blockIdx.x & 3;
    __shared__ float xs[256][17], h1s[256][17], h2s[256][17];
    __shared__ float as[16][17];
    int t = threadIdx.x;
    as[t>>4][t&15] = a[t];
    for (int idx=t; idx<4096; idx+=256){
        int w = idx >> 8, hc = idx & 255;
        xs[hc][w] = bf2f(h[((size_t)(n*16 + w)*LSEQ + TT + tt)*HD + hc]);
    }
    __syncthreads();
    for (int idx=t; idx<4096; idx+=256){
        int v = idx & 15, hc = idx >> 4;
        float acc = 0.f;
        #pragma unroll
        for (int w=0;w<16;w++) acc += as[v][w]*xs[hc][w];
        h1s[hc][v] = acc;
    }
    __syncthreads();
    for (int idx=t; idx<4096; idx+=256){
        int v = idx & 15, hc = idx >> 4;
        float acc = 0.f;
        #pragma unroll
        for (int w=0;w<16;w++) acc += as[v][w]*h1s[hc][w];
        h2s[hc][v] = acc;
    }
    __syncthreads();
    int hc = t;
    #pragma unroll
    for (int w=0;w<16;w++){
        size_t row = (size_t)((n*16 + w)*4 + tt);
        amid[row*768 +       hc] = f2bf(xs[hc][w]);
        amid[row*768 + 256 + hc] = f2bf(h1s[hc][w]);
        amid[row*768 + 512 + hc] = f2bf(h2s[hc][w]);
    }
}

// ---------------- head ----------------
__global__ __launch_bounds__(256)
void k_z(const u16* __restrict__ h, u16* __restrict__ z)
{
    int bid = blockIdx.x, t = threadIdx.x;     // bid = n*16+c
    #pragma unroll
    for (int tc=0;tc<4;tc++)
        z[((size_t)bid*4 + tc)*HD + t] = f2bf(tanhf(bf2f(h[((size_t)bid*LSEQ + TT + tc)*HD + t])));
}

__global__ __launch_bounds__(256)
void k_head1p(const u16* __restrict__ z, const float* __restrict__ Wd1,
              float* __restrict__ d1p)
{
    __shared__ float zch[64][137];
    __shared__ float wt[16][137];
    int t = threadIdx.x;
    int col = t & 15, rgrp = t >> 4;
    int ob = blockIdx.x * 16;
    int kb = blockIdx.y;
    float acc[4] = {0.f,0.f,0.f,0.f};
    for (int kc=0; kc<1024; kc+=128){
        int base_k = kb*1024 + kc;
        #pragma unroll
        for (int jj=0; jj<16; jj++){
            int idx = t + jj*256;
            int n = idx >> 6, k2 = (idx & 63) << 1;
            u32 r = *(const u32*)&z[(size_t)n*16384 + base_k + k2];
            zch[n][k2] = lo16(r); zch[n][k2+1] = hi16(r);
        }
        #pragma unroll
        for (int jj=0; jj<2; jj++){
            int idx = t + jj*256;
            int r = idx >> 5, k4 = (idx & 31) << 2;
            float4 w4 = *(const float4*)&Wd1[(size_t)(ob + r)*16384 + base_k + k4];
            wt[r][k4] = w4.x; wt[r][k4+1] = w4.y; wt[r][k4+2] = w4.z; wt[r][k4+3] = w4.w;
        }
        __syncthreads();
        for (int k=0;k<128;k++){
            float wv = wt[col][k];
            #pragma unroll
            for (int u=0;u<4;u++) acc[u] += zch[rgrp + 16*u][k]*wv;
        }
        __syncthreads();
    }
    #pragma unroll
    for (int u=0;u<4;u++)
        d1p[(size_t)(kb*64 + rgrp + 16*u)*HD + ob + col] = acc[u];
}

__global__ __launch_bounds__(256)
void k_headf(const float* __restrict__ d1p, const float* __restrict__ bd1,
             const float* __restrict__ Wd2, const float* __restrict__ bd2,
             float* __restrict__ out)
{
    __shared__ float red[4];
    int n = blockIdx.x, c = threadIdx.x;
    float s = 0.f;
    #pragma unroll
    for (int kb=0; kb<16; kb++) s += d1p[(size_t)(kb*64 + n)*HD + c];
    float xx = s + bd1[c];
    float ge = 0.5f*xx*(1.f + erff(xx*0.70710678118654752f));
    float p = ge * Wd2[c];
    #pragma unroll
    for (int m=1;m<64;m<<=1) p += __shfl_xor(p, m, 64);
    if ((c & 63) == 0) red[c >> 6] = p;
    __syncthreads();
    if (c == 0) out[n] = red[0]+red[1]+red[2]+red[3] + bd2[0];
}

// ---------------- launch ----------------
extern "C" void kernel_launch(void* const* d_in, const int* in_sizes, int n_in,
                              void* d_out, int out_size, void* d_ws, size_t ws_size,
                              hipStream_t stream)
{
    const float* x    = (const float*)d_in[0];
    const float* Wfc  = (const float*)d_in[3];
    const float* bfc  = (const float*)d_in[4];
    const float* cls  = (const float*)d_in[5];
    const float* pos  = (const float*)d_in[6];
    const float* emb1 = (const float*)d_in[7];
    const float* emb2 = (const float*)d_in[8];
    const float* Wl1  = (const float*)d_in[9];
    const float* bl1  = (const float*)d_in[10];
    const float* Wl2  = (const float*)d_in[11];
    const float* bl2  = (const float*)d_in[12];
    const float* Wqkv = (const float*)d_in[13];
    const float* bqkv = (const float*)d_in[14];
    const float* Wo   = (const float*)d_in[15];
    const float* bo   = (const float*)d_in[16];
    const float* W1   = (const float*)d_in[17];
    const float* b1   = (const float*)d_in[18];
    const float* W2   = (const float*)d_in[19];
    const float* b2   = (const float*)d_in[20];
    const float* ln1g = (const float*)d_in[21];
    const float* ln1b = (const float*)d_in[22];
    const float* ln2g = (const float*)d_in[23];
    const float* ln2b = (const float*)d_in[24];
    const float* Wmlp = (const float*)d_in[25];
    const float* bmlp = (const float*)d_in[26];
    const float* Wd1  = (const float*)d_in[27];
    const float* bd1  = (const float*)d_in[28];
    const float* Wd2  = (const float*)d_in[29];
    const float* bd2  = (const float*)d_in[30];

    // dynamic chunk selection (2048 B/token)
    int NCH = 8;
    {
        const size_t fixed = 63145088 + (1<<20);
        if      (fixed + (size_t)MTOK    *2048 <= ws_size) NCH = 1;
        else if (fixed + (size_t)(MTOK/2)*2048 <= ws_size) NCH = 2;
        else if (fixed + (size_t)(MTOK/4)*2048 <= ws_size) NCH = 4;
    }
    const int RCH = MTOK / NCH;
    const int SCH = BSEQ / NCH;

    // workspace layout
    u16* h    = (u16*)d_ws;                    // 26,214,400 u16
    u16* buf  = h    + (size_t)MTOK*HD;        // RCH*1024  (qkv / ff1 / mixprop amid)
    u16* wq   = buf  + (size_t)RCH*1024;       //    786,432
    u16* wo   = wq   + (size_t)4*768*256;      //    262,144
    u16* w1   = wo   + (size_t)4*256*256;      //  1,048,576
    u16* w2   = w1   + (size_t)4*1024*256;     //  1,048,576
    u16* wmb  = w2   + (size_t)4*256*1024;     //    589,824
    u16* zb   = wmb  + (size_t)3*256*768;      //  1,048,576
    float* fp = (float*)(zb + (size_t)BSZ*16384);
    float* m1  = fp;
    float* m2  = m1 + CCH*HD;
    float* an  = m2 + CCH*HD;
    float* d1p = an + CCH*CCH;                 // 16*64*256

    // one-time weight prep
    k_cvt<<<512, 256, 0, stream>>>(Wqkv, wq, 4*768*256);
    k_cvt<<<256, 256, 0, stream>>>(Wo,   wo, 4*256*256);
    k_cvt<<<512, 256, 0, stream>>>(W1,   w1, 4*1024*256);
    k_cvt<<<512, 256, 0, stream>>>(W2,   w2, 4*256*1024);
    k_cvt<<<256, 256, 0, stream>>>(Wmlp, wmb, 3*256*768);

    k_embed<<<BSEQ, 256, 0, stream>>>(x, Wfc, bfc, cls, pos, h);
    k_graph_m<<<16, 256, 0, stream>>>(emb1, Wl1, bl1, m1);
    k_graph_m<<<16, 256, 0, stream>>>(emb2, Wl2, bl2, m2);
    k_graph_a<<<1, 256, 0, stream>>>(m1, m2, an);

    for (int l=0; l<NLAY; l++){
        if (l > 0){
            k_mixprep<<<BSZ*NCLS, 256, 0, stream>>>(h, an, buf);
            k_gemmA<<<dim3(256/128, 4096/128), 256, 0, stream>>>(
                buf, 768, wmb + (size_t)(l-1)*256*768, bmlp + (size_t)(l-1)*HD,
                h, HD, 768, 0, 1);
        }

        for (int c=0; c<NCH; c++){
            size_t row0 = (size_t)c * RCH;
            k_gemmA<<<dim3(768/128, RCH/128), 256, 0, stream>>>(
                h + row0*HD, HD, wq + (size_t)l*768*256, bqkv + (size_t)l*768,
                buf, 768, HD, 0, 0);
            k_attn<<<SCH*NHEAD/2, 256, 0, stream>>>(buf);
            // out-proj + residual + LN1 fused (reads q-slot of buf, lda=768)
            k_gemmC<<<RCH/64, 256, 0, stream>>>(
                buf, 768, HD, wo + (size_t)l*256*256, bo + (size_t)l*HD,
                h, ln1g + (size_t)l*HD, ln1b + (size_t)l*HD, row0);
            k_gemmA<<<dim3(1024/128, RCH/128), 256, 0, stream>>>(
                h + row0*HD, HD, w1 + (size_t)l*1024*256, b1 + (size_t)l*1024,
                buf, 1024, HD, 1, 0);
            // FF2 + residual + LN2 fused
            k_gemmC<<<RCH/64, 256, 0, stream>>>(
                buf, 1024, 1024, w2 + (size_t)l*256*1024, b2 + (size_t)l*HD,
                h, ln2g + (size_t)l*HD, ln2b + (size_t)l*HD, row0);
        }
    }

    k_z<<<BSZ*CCH, 256, 0, stream>>>(h, zb);
    k_head1p<<<dim3(16, 16), 256, 0, stream>>>(zb, Wd1, d1p);
    k_headf<<<BSZ, 256, 0, stream>>>(d1p, bd1, Wd2, bd2, (float*)d_out);
}

// Round 9
// 1988.675 us; speedup vs baseline: 2.0537x; 2.0537x over previous
//
#include <hip/hip_runtime.h>
#include <hip/hip_bf16.h>
#include <math.h>

typedef unsigned short u16;
typedef unsigned int   u32;
typedef __attribute__((ext_vector_type(8))) short short8;   // 8 bf16 = 4 VGPRs
typedef __attribute__((ext_vector_type(4))) float f32x4;

// ---- model dims ----
#define BSZ   64
#define TT    96
#define CCH   16
#define INDIM 16
#define HD    256
#define NHEAD 8
#define DHEAD 32
#define NCLS  4
#define LSEQ  100      // TT + NCLS
#define NLAY  4
#define EPSV  1e-5f
#define BSEQ  (BSZ*CCH)        // 1024 sequences
#define MTOK  (BSEQ*LSEQ)      // 102400 tokens

#if __has_builtin(__builtin_amdgcn_exp2f)
#define EXP2F __builtin_amdgcn_exp2f
#else
#define EXP2F exp2f
#endif

__device__ __forceinline__ float bf2f(u16 x){ return __uint_as_float(((u32)x)<<16); }
__device__ __forceinline__ u16 f2bf(float f){
    u32 u = __float_as_uint(f);
    u32 r = (u + 0x7fffu + ((u>>16)&1u)) >> 16;
    return (u16)r;
}
__device__ __forceinline__ float lo16(u32 r){ return __uint_as_float(r<<16); }
__device__ __forceinline__ float hi16(u32 r){ return __uint_as_float(r&0xffff0000u); }

// HW packed f32->bf16 (RNE), 1 instr per 2 elements
__device__ __forceinline__ u32 cvtpk(float lo, float hi){
    u32 r;
    asm("v_cvt_pk_bf16_f32 %0, %1, %2" : "=v"(r) : "v"(lo), "v"(hi));
    return r;
}

// async global->LDS, 16B per lane; LDS dest = (wave-uniform base) + lane*16
__device__ __forceinline__ void gload_lds16(const u16* g, u16* l){
    __builtin_amdgcn_global_load_lds(
        (const __attribute__((address_space(1))) unsigned int*)g,
        (__attribute__((address_space(3))) unsigned int*)l, 16, 0, 0);
}

// ---------------- f32 -> bf16 bulk convert ----------------
__global__ __launch_bounds__(256)
void k_cvt(const float* __restrict__ src, u16* __restrict__ dst, int n)
{
    for (int i = blockIdx.x*256 + threadIdx.x; i < n; i += gridDim.x*256)
        dst[i] = f2bf(src[i]);
}

// ---------------- embed ----------------
__global__ __launch_bounds__(256)
void k_embed(const float* __restrict__ x, const float* __restrict__ Wfc,
             const float* __restrict__ bfc, const float* __restrict__ cls,
             const float* __restrict__ pos, u16* __restrict__ h)
{
    int s = blockIdx.x;                // 0..1023 = n*16 + c
    int n = s >> 4, c = s & 15;
    int hc = threadIdx.x;
    float wr[INDIM];
    #pragma unroll
    for (int i=0;i<INDIM;i++) wr[i] = Wfc[hc*INDIM + i];
    float bb = bfc[hc];
    for (int l=0; l<TT; l++){
        const float* xr = x + (size_t)((n*TT + l)*CCH + c)*INDIM;
        float acc = bb;
        #pragma unroll
        for (int i=0;i<INDIM;i++) acc += xr[i]*wr[i];
        acc += pos[(size_t)(l*CCH + c)*HD + hc];
        h[((size_t)s*LSEQ + l)*HD + hc] = f2bf(acc);
    }
    #pragma unroll
    for (int l=TT; l<LSEQ; l++){
        float v = cls[(size_t)((l-TT)*CCH + c)*HD + hc]
                + pos[(size_t)(l*CCH + c)*HD + hc];
        h[((size_t)s*LSEQ + l)*HD + hc] = f2bf(v);
    }
}

// ---------------- graph constructor ----------------
__global__ __launch_bounds__(256)
void k_graph_m(const float* __restrict__ emb, const float* __restrict__ Wl,
               const float* __restrict__ bl, float* __restrict__ m)
{
    int r = blockIdx.x, o = threadIdx.x;
    __shared__ float e[HD];
    e[o] = emb[r*HD + o];
    __syncthreads();
    const float* w = Wl + (size_t)o*HD;
    float acc = bl[o];
    for (int k=0;k<HD;k++) acc += e[k]*w[k];
    m[r*HD + o] = tanhf(acc);
}

__global__ __launch_bounds__(256)
void k_graph_a(const float* __restrict__ m1, const float* __restrict__ m2,
               float* __restrict__ a)
{
    int t = threadIdx.x; int v = t >> 4, w = t & 15;
    __shared__ float adj[16][17];
    float s1=0.f, s2=0.f;
    for (int k=0;k<HD;k++){
        s1 += m1[v*HD+k]*m2[w*HD+k];
        s2 += m2[v*HD+k]*m1[w*HD+k];
    }
    float g = tanhf(s1 - s2); g = g > 0.f ? g : 0.f;
    adj[v][w] = g + (v==w ? 1.f : 0.f);
    __syncthreads();
    float rs = 0.f;
    #pragma unroll
    for (int j=0;j<16;j++) rs += adj[v][j];
    a[t] = adj[v][w] / rs;
}

// ---------------- MFMA GEMM, BK=64, counted-vmcnt 2-ahead pipeline ----------
// grid = dim3(N/128, M/128) + XCD swizzle. Stage tile ts+2 into freed buffer;
// wait vmcnt(8) = "tile ts landed, ts+1 still flying" (no per-step drain).
// Epilogue: C tile staged in LDS, cooperative dwordx4 stores.
__global__ __launch_bounds__(256)
void k_gemmA(const u16* __restrict__ A, int lda,
             const u16* __restrict__ W, const float* __restrict__ bias,
             u16* __restrict__ C, int ldc, int K, int relu, int scat)
{
    __shared__ u16 smem[32768];            // 64 KB union
    u16* As0 = smem;                       // [2][4096]
    u16* As1 = smem + 8192;                // [2][4096]
    u16* Ws0 = smem + 16384;               // [2][4096]
    u16* Ws1 = smem + 24576;               // [2][4096]

    int t = threadIdx.x;
    int lane = t & 63, w = t >> 6;
    int wm = (w & 1)*64, wn = (w >> 1)*64;
    int fr = lane & 15, quad = lane >> 4;

    // XCD-aware tile remap (bijective; all grids here are %8==0)
    int nwg = gridDim.x * gridDim.y;
    int bid = blockIdx.y * gridDim.x + blockIdx.x;
    int tile = bid;
    if (!(nwg & 7)){
        int cpx = nwg >> 3;
        tile = (bid & 7)*cpx + (bid >> 3);
    }
    int bx = tile % gridDim.x, by = tile / gridDim.x;
    size_t mb = (size_t)by * 128;
    int nb = bx * 128;

    int srow = lane >> 2;
    int sslot = lane & 3;

    f32x4 acc[4][4] = {};

    auto STAGE = [&](int bb, int k0){     // 8 gloads per thread
        #pragma unroll
        for (int i=0;i<2;i++){
            int r = w*32 + i*16 + srow;
            int cw = sslot ^ ((r>>1)&3);
            gload_lds16(&A[(mb + r)*(size_t)lda + k0      + cw*8], &As0[bb*4096 + (w*32 + i*16)*32]);
            gload_lds16(&A[(mb + r)*(size_t)lda + k0 + 32 + cw*8], &As1[bb*4096 + (w*32 + i*16)*32]);
            gload_lds16(&W[(size_t)(nb + r)*K   + k0      + cw*8], &Ws0[bb*4096 + (w*32 + i*16)*32]);
            gload_lds16(&W[(size_t)(nb + r)*K   + k0 + 32 + cw*8], &Ws1[bb*4096 + (w*32 + i*16)*32]);
        }
    };
    auto COMPUTE = [&](int bb){
        short8 af0[4], af1[4], bf0[4], bf1[4];
        #pragma unroll
        for (int mt=0; mt<4; mt++){
            int r = wm + mt*16 + fr;
            int sw = (quad ^ ((r>>1)&3)) << 3;
            af0[mt] = *(const short8*)&As0[bb*4096 + r*32 + sw];
            af1[mt] = *(const short8*)&As1[bb*4096 + r*32 + sw];
        }
        #pragma unroll
        for (int nt=0; nt<4; nt++){
            int r = wn + nt*16 + fr;
            int sw = (quad ^ ((r>>1)&3)) << 3;
            bf0[nt] = *(const short8*)&Ws0[bb*4096 + r*32 + sw];
            bf1[nt] = *(const short8*)&Ws1[bb*4096 + r*32 + sw];
        }
        #pragma unroll
        for (int mt=0; mt<4; mt++)
            #pragma unroll
            for (int nt=0; nt<4; nt++){
                acc[mt][nt] = __builtin_amdgcn_mfma_f32_16x16x32_bf16(
                    af0[mt], bf0[nt], acc[mt][nt], 0, 0, 0);
                acc[mt][nt] = __builtin_amdgcn_mfma_f32_16x16x32_bf16(
                    af1[mt], bf1[nt], acc[mt][nt], 0, 0, 0);
            }
    };

    const int nst = K >> 6;
    STAGE(0, 0);
    if (nst > 1) STAGE(1, 64);
    int b = 0;
    for (int ts = 0; ts < nst; ++ts){
        if (ts + 1 < nst) asm volatile("s_waitcnt vmcnt(8)" ::: "memory");
        else              asm volatile("s_waitcnt vmcnt(0)" ::: "memory");
        __builtin_amdgcn_s_barrier();
        COMPUTE(b);
        __builtin_amdgcn_s_barrier();
        if (ts + 2 < nst) STAGE(b, (ts+2) << 6);
        b ^= 1;
    }

    // ---- epilogue: bias(+relu) -> LDS tile -> coalesced dwordx4 stores ----
    float bb4[4];
    #pragma unroll
    for (int nt=0; nt<4; nt++) bb4[nt] = bias[nb + wn + nt*16 + fr];
    u16* Ct = smem;                        // 128x128 u16
    #pragma unroll
    for (int mt=0; mt<4; mt++){
        int rw = wm + mt*16 + quad*4;
        #pragma unroll
        for (int nt=0; nt<4; nt++){
            int col = wn + nt*16 + fr;
            float v0 = acc[mt][nt][0] + bb4[nt];
            float v1 = acc[mt][nt][1] + bb4[nt];
            float v2 = acc[mt][nt][2] + bb4[nt];
            float v3 = acc[mt][nt][3] + bb4[nt];
            if (relu){
                v0 = v0 > 0.f ? v0 : 0.f;  v1 = v1 > 0.f ? v1 : 0.f;
                v2 = v2 > 0.f ? v2 : 0.f;  v3 = v3 > 0.f ? v3 : 0.f;
            }
            u32 p01 = cvtpk(v0, v1), p23 = cvtpk(v2, v3);
            Ct[(rw+0)*128 + col] = (u16)p01;
            Ct[(rw+1)*128 + col] = (u16)(p01 >> 16);
            Ct[(rw+2)*128 + col] = (u16)p23;
            Ct[(rw+3)*128 + col] = (u16)(p23 >> 16);
        }
    }
    __syncthreads();
    #pragma unroll
    for (int it=0; it<8; ++it){
        int row = it*16 + (t>>4);
        int seg = t & 15;
        size_t rg = mb + row;
        if (scat) rg = (rg >> 2)*LSEQ + TT + (rg & 3);
        *(short8*)&C[rg*(size_t)ldc + nb + seg*8] = *(const short8*)&Ct[row*128 + seg*8];
    }
}

// ------- MFMA GEMM (N=256) + bias + residual + LayerNorm fused, in-place h -------
// BM=64, BN=256, BK=64; wave w owns 64x64 sub-tile. Counted-vmcnt 2-ahead pipeline
// (10 gloads/thread per STAGE -> vmcnt(10)). LN epilogue via LDS cross-wave reduction.
__global__ __launch_bounds__(256)
void k_gemmC(const u16* __restrict__ A, int lda, int K,
             const u16* __restrict__ W, const float* __restrict__ bias,
             u16* __restrict__ h, const float* __restrict__ gam,
             const float* __restrict__ bet, size_t row0)
{
    __shared__ u16 smem[40960];            // 80 KB union
    u16* As0 = smem;                       // [2][2048]
    u16* As1 = smem + 4096;                // [2][2048]
    u16* Ws0 = smem + 8192;                // [2][8192]
    u16* Ws1 = smem + 24576;               // [2][8192]

    int t = threadIdx.x;
    int lane = t & 63, w = t >> 6;
    int fr = lane & 15, quad = lane >> 4;
    size_t mb = (size_t)blockIdx.x * 64;
    int srow = lane >> 2, sslot = lane & 3;

    f32x4 acc[4][4] = {};

    auto STAGE = [&](int bb, int k0){     // 10 gloads per thread
        {
            int r = w*16 + srow;
            int cw = sslot ^ ((r>>1)&3);
            gload_lds16(&A[(mb + r)*(size_t)lda + k0      + cw*8], &As0[bb*2048 + (w*16)*32]);
            gload_lds16(&A[(mb + r)*(size_t)lda + k0 + 32 + cw*8], &As1[bb*2048 + (w*16)*32]);
        }
        #pragma unroll
        for (int i=0;i<4;i++){
            int r = w*64 + i*16 + srow;
            int cw = sslot ^ ((r>>1)&3);
            gload_lds16(&W[(size_t)r*K + k0      + cw*8], &Ws0[bb*8192 + (w*64 + i*16)*32]);
            gload_lds16(&W[(size_t)r*K + k0 + 32 + cw*8], &Ws1[bb*8192 + (w*64 + i*16)*32]);
        }
    };
    auto COMPUTE = [&](int bb){
        short8 af0[4], af1[4], bf0[4], bf1[4];
        #pragma unroll
        for (int mt=0; mt<4; mt++){
            int ra = mt*16 + fr;
            int swa = (quad ^ ((ra>>1)&3)) << 3;
            af0[mt] = *(const short8*)&As0[bb*2048 + ra*32 + swa];
            af1[mt] = *(const short8*)&As1[bb*2048 + ra*32 + swa];
        }
        #pragma unroll
        for (int nt=0; nt<4; nt++){
            int rb = w*64 + nt*16 + fr;
            int swb = (quad ^ ((rb>>1)&3)) << 3;
            bf0[nt] = *(const short8*)&Ws0[bb*8192 + rb*32 + swb];
            bf1[nt] = *(const short8*)&Ws1[bb*8192 + rb*32 + swb];
        }
        #pragma unroll
        for (int mt=0; mt<4; mt++)
            #pragma unroll
            for (int nt=0; nt<4; nt++){
                acc[mt][nt] = __builtin_amdgcn_mfma_f32_16x16x32_bf16(
                    af0[mt], bf0[nt], acc[mt][nt], 0, 0, 0);
                acc[mt][nt] = __builtin_amdgcn_mfma_f32_16x16x32_bf16(
                    af1[mt], bf1[nt], acc[mt][nt], 0, 0, 0);
            }
    };

    const int nst = K >> 6;
    STAGE(0, 0);
    if (nst > 1) STAGE(1, 64);
    int b = 0;
    for (int ts = 0; ts < nst; ++ts){
        if (ts + 1 < nst) asm volatile("s_waitcnt vmcnt(10)" ::: "memory");
        else              asm volatile("s_waitcnt vmcnt(0)"  ::: "memory");
        __builtin_amdgcn_s_barrier();
        COMPUTE(b);
        __builtin_amdgcn_s_barrier();
        if (ts + 2 < nst) STAGE(b, (ts+2) << 6);
        b ^= 1;
    }

    // ---- epilogue: v = acc + bias + residual ----
    float bb4[4], gg[4], be[4];
    #pragma unroll
    for (int nt=0; nt<4; nt++){
        int col = w*64 + nt*16 + fr;
        bb4[nt] = bias[col]; gg[nt] = gam[col]; be[nt] = bet[col];
    }
    #pragma unroll
    for (int mt=0; mt<4; mt++){
        #pragma unroll
        for (int r=0; r<4; r++){
            size_t row = row0 + mb + mt*16 + quad*4 + r;
            #pragma unroll
            for (int nt=0; nt<4; nt++)
                acc[mt][nt][r] += bb4[nt] + bf2f(h[row*HD + w*64 + nt*16 + fr]);
        }
    }
    __syncthreads();
    float* red  = (float*)smem;            // 256 f32
    float* red2 = (float*)(smem + 512);    // 256 f32
    float ps[4][4];
    #pragma unroll
    for (int mt=0; mt<4; mt++)
        #pragma unroll
        for (int r=0; r<4; r++){
            float s = acc[mt][0][r] + acc[mt][1][r] + acc[mt][2][r] + acc[mt][3][r];
            s += __shfl_xor(s,1,64); s += __shfl_xor(s,2,64);
            s += __shfl_xor(s,4,64); s += __shfl_xor(s,8,64);
            ps[mt][r] = s;
        }
    if (fr == 0){
        #pragma unroll
        for (int mt=0; mt<4; mt++)
            #pragma unroll
            for (int r=0; r<4; r++)
                red[w*64 + mt*16 + quad*4 + r] = ps[mt][r];
    }
    __syncthreads();
    float mean[4][4];
    #pragma unroll
    for (int mt=0; mt<4; mt++)
        #pragma unroll
        for (int r=0; r<4; r++){
            int rl = mt*16 + quad*4 + r;
            mean[mt][r] = (red[rl] + red[64+rl] + red[128+rl] + red[192+rl]) * (1.f/256.f);
            float s = 0.f;
            #pragma unroll
            for (int nt=0; nt<4; nt++){ float d = acc[mt][nt][r] - mean[mt][r]; s += d*d; }
            s += __shfl_xor(s,1,64); s += __shfl_xor(s,2,64);
            s += __shfl_xor(s,4,64); s += __shfl_xor(s,8,64);
            ps[mt][r] = s;
        }
    if (fr == 0){
        #pragma unroll
        for (int mt=0; mt<4; mt++)
            #pragma unroll
            for (int r=0; r<4; r++)
                red2[w*64 + mt*16 + quad*4 + r] = ps[mt][r];
    }
    __syncthreads();
    // ---- normalize -> LDS tile -> coalesced stores ----
    u16* Ct = smem + 8192;                 // 64x256 u16
    #pragma unroll
    for (int mt=0; mt<4; mt++)
        #pragma unroll
        for (int r=0; r<4; r++){
            int rl = mt*16 + quad*4 + r;
            float inv = rsqrtf((red2[rl] + red2[64+rl] + red2[128+rl] + red2[192+rl])
                               * (1.f/256.f) + EPSV);
            float o0 = (acc[mt][0][r] - mean[mt][r]) * inv * gg[0] + be[0];
            float o1 = (acc[mt][1][r] - mean[mt][r]) * inv * gg[1] + be[1];
            float o2 = (acc[mt][2][r] - mean[mt][r]) * inv * gg[2] + be[2];
            float o3 = (acc[mt][3][r] - mean[mt][r]) * inv * gg[3] + be[3];
            u32 p01 = cvtpk(o0, o1), p23 = cvtpk(o2, o3);
            Ct[rl*256 + w*64 +  0 + fr] = (u16)p01;
            Ct[rl*256 + w*64 + 16 + fr] = (u16)(p01 >> 16);
            Ct[rl*256 + w*64 + 32 + fr] = (u16)p23;
            Ct[rl*256 + w*64 + 48 + fr] = (u16)(p23 >> 16);
        }
    __syncthreads();
    #pragma unroll
    for (int it=0; it<8; ++it){
        int row = it*8 + (t>>5);
        int seg = t & 31;
        *(short8*)&h[(row0 + mb + row)*HD + seg*8] = *(const short8*)&Ct[row*256 + seg*8];
    }
}

// ---------------- MFMA attention with causal tile-skipping (r7 version) ----------------
#define KS_STR 40
#define VT_STR 136
__global__ __launch_bounds__(256)
void k_attn(u16* __restrict__ qkv)
{
    __shared__ u16 smem[17664];   // stage: Ks 2x4480 @0 | Vt 2x4352 @8960
                                  // strips: Ph 4x2048 @0 (over Ks) | Pv 4x2048 @8960 (over Vt)
    int t = threadIdx.x;
    int w = t >> 6, lane = t & 63;
    int fr = lane & 15, quad = lane >> 4;
    int p = t >> 7, t2 = t & 127;
    u16* Ks = smem + p*4480;
    u16* Vt = smem + 8960 + p*4352;

    {
        int gp = blockIdx.x*2 + p;
        size_t base = (size_t)(gp >> 3)*LSEQ*768 + (gp & 7)*32;
        for (int idx = t2; idx < 1792; idx += 128){
            int key = idx >> 4, d2 = (idx & 15) << 1;
            u32 kv = (key < LSEQ) ? *(const u32*)&qkv[base + (size_t)key*768 + 256 + d2] : 0u;
            *(u32*)&Ks[key*KS_STR + d2] = kv;
        }
        // key-major V transpose staging: lanes stride-1 in key -> conflict-free writes
        for (int idx = t2; idx < 2048; idx += 128){
            int key = idx & 127, d2 = (idx >> 7) << 1;
            u32 vv = (key < LSEQ) ? *(const u32*)&qkv[base + (size_t)key*768 + 512 + d2] : 0u;
            Vt[ d2   *VT_STR + key] = (u16)(vv & 0xffffu);
            Vt[(d2+1)*VT_STR + key] = (u16)(vv >> 16);
        }
    }
    __syncthreads();

    int wp = w >> 1;
    int gp = blockIdx.x*2 + wp;
    size_t base = (size_t)(gp >> 3)*LSEQ*768 + (gp & 7)*32;
    u16* Ksw = smem + wp*4480;
    u16* Vtw = smem + 8960 + wp*4352;

    short8 kf[7];
    #pragma unroll
    for (int nt=0; nt<7; nt++)
        kf[nt] = *(const short8*)&Ksw[(nt*16 + fr)*KS_STR + quad*8];
    short8 vfr[4][2];
    #pragma unroll
    for (int ks=0; ks<4; ks++)
        #pragma unroll
        for (int nt=0; nt<2; nt++)
            vfr[ks][nt] = *(const short8*)&Vtw[(nt*16 + fr)*VT_STR + ks*32 + quad*8];

    const int smask = (w & 1) ? 0x34 : 0x4B;   // strips {2,4,5} / {0,1,3,6}
    // prefetch q fragments for this wave's strips (before any output store can alias)
    short8 qfs[7];
    #pragma unroll
    for (int st=0; st<7; ++st){
        if (!((smask >> st) & 1)) continue;
        int q = st*16 + fr;
        short8 z = {};
        qfs[st] = (q < LSEQ) ? *(const short8*)&qkv[base + (size_t)q*768 + quad*8] : z;
    }
    __syncthreads();   // all waves done reading Ks/Vt before Ph/Pv overlay reuse

    u16* Ph = smem + w*2048;           // P_hi over dead Ks region
    u16* Pv = smem + 8960 + w*2048;    // P_lo over dead Vt region

    const float cs = 0.17677669529663687f * 1.4426950408889634f;  // (1/sqrt32)*log2(e)
    #pragma unroll
    for (int st = 0; st < 7; ++st){
        if (!((smask >> st) & 1)) continue;
        const int ntile = (st == 6) ? 7 : (st + 1);
        const int nks   = (st == 6) ? 4 : (st/2 + 1);
        f32x4 S[7];
        #pragma unroll
        for (int nt=0; nt<7; nt++){
            if (nt >= ntile) continue;
            f32x4 z = {};
            S[nt] = __builtin_amdgcn_mfma_f32_16x16x32_bf16(qfs[st], kf[nt], z, 0,0,0);
        }
        // scale (in log2 domain); mask ONLY the last tile (full tiles causal-valid)
        float mx[4] = {-1e30f,-1e30f,-1e30f,-1e30f};
        #pragma unroll
        for (int nt=0;nt<7;nt++){
            if (nt >= ntile) continue;
            #pragma unroll
            for (int r=0;r<4;r++){
                float s = S[nt][r]*cs;
                if (nt == ntile-1){
                    int qr = st*16 + quad*4 + r;
                    int jmax = (qr < TT) ? qr : (LSEQ-1);
                    s = ((nt*16 + fr) <= jmax) ? s : -1e30f;
                }
                S[nt][r] = s;
                mx[r] = fmaxf(mx[r], s);
            }
        }
        #pragma unroll
        for (int r=0;r<4;r++){
            #pragma unroll
            for (int m=1;m<16;m<<=1) mx[r] = fmaxf(mx[r], __shfl_xor(mx[r], m, 64));
        }
        float l4[4] = {0.f,0.f,0.f,0.f};
        #pragma unroll
        for (int r=0;r<4;r++){
            #pragma unroll
            for (int nt=0;nt<7;nt++){
                if (nt >= ntile) continue;
                float pv = EXP2F(S[nt][r] - mx[r]);
                S[nt][r] = pv;
                l4[r] += pv;
            }
        }
        #pragma unroll
        for (int r=0;r<4;r++){
            #pragma unroll
            for (int m=1;m<16;m<<=1) l4[r] += __shfl_xor(l4[r], m, 64);
        }
        // WAR fence: previous strip's Ph/Pv reads must complete before overwrite
        asm volatile("s_waitcnt lgkmcnt(0)" ::: "memory");
        // write P_hi + P_lo via packed cvt; panel layout [ks][16 rows][32 k], XOR swizzle
        #pragma unroll
        for (int nt=0;nt<7;nt++){
            if (nt >= ntile) continue;
            u32 h01 = cvtpk(S[nt][0], S[nt][1]);
            u32 h23 = cvtpk(S[nt][2], S[nt][3]);
            float l0 = S[nt][0] - lo16(h01);
            float l1 = S[nt][1] - hi16(h01);
            float l2 = S[nt][2] - lo16(h23);
            float l3 = S[nt][3] - hi16(h23);
            u32 g01 = cvtpk(l0, l1);
            u32 g23 = cvtpk(l2, l3);
            u16 hv[4] = {(u16)h01, (u16)(h01>>16), (u16)h23, (u16)(h23>>16)};
            u16 lv[4] = {(u16)g01, (u16)(g01>>16), (u16)g23, (u16)(g23>>16)};
            #pragma unroll
            for (int r=0;r<4;r++){
                int row = quad*4 + r;
                int a = (nt>>1)*512 + row*32 + ((((nt&1)<<4) + fr) ^ (((row>>1)&3)<<3));
                Ph[a] = hv[r];
                Pv[a] = lv[r];
            }
        }
        if (ntile*16 < nks*32){
            #pragma unroll
            for (int r=0;r<4;r++){
                int row = quad*4 + r;
                int a = (ntile>>1)*512 + row*32 + ((((ntile&1)<<4) + fr) ^ (((row>>1)&3)<<3));
                Ph[a] = 0;
                Pv[a] = 0;
            }
        }
        asm volatile("s_waitcnt lgkmcnt(0)" ::: "memory");
        f32x4 D[2] = {};
        #pragma unroll
        for (int ks=0; ks<4; ks++){
            if (ks >= nks) continue;
            int a = ks*512 + fr*32 + ((quad ^ ((fr>>1)&3)) << 3);
            short8 ph = *(const short8*)&Ph[a];
            short8 pl = *(const short8*)&Pv[a];
            #pragma unroll
            for (int nt=0; nt<2; nt++){
                D[nt] = __builtin_amdgcn_mfma_f32_16x16x32_bf16(ph, vfr[ks][nt], D[nt], 0,0,0);
                D[nt] = __builtin_amdgcn_mfma_f32_16x16x32_bf16(pl, vfr[ks][nt], D[nt], 0,0,0);
            }
        }
        #pragma unroll
        for (int r=0;r<4;r++){
            int qr = st*16 + quad*4 + r;
            if (qr < LSEQ){
                float inv = 1.f / l4[r];
                u32 o = cvtpk(D[0][r]*inv, D[1][r]*inv);
                qkv[base + (size_t)qr*768 +      fr] = (u16)o;
                qkv[base + (size_t)qr*768 + 16 + fr] = (u16)(o >> 16);
            }
        }
        // no trailing drain: next strip's WAR fence orders LDS; global rows disjoint
    }
}

// ---------------- mixprop prep ----------------
__global__ __launch_bounds__(256)
void k_mixprep(const u16* __restrict__ h, const float* __restrict__ a,
               u16* __restrict__ amid)
{
    int n = blockIdx.x >> 2, tt = blockIdx.x & 3;
    __shared__ float xs[256][17], h1s[256][17], h2s[256][17];
    __shared__ float as[16][17];
    int t = threadIdx.x;
    as[t>>4][t&15] = a[t];
    for (int idx=t; idx<4096; idx+=256){
        int w = idx >> 8, hc = idx & 255;
        xs[hc][w] = bf2f(h[((size_t)(n*16 + w)*LSEQ + TT + tt)*HD + hc]);
    }
    __syncthreads();
    for (int idx=t; idx<4096; idx+=256){
        int v = idx & 15, hc = idx >> 4;
        float acc = 0.f;
        #pragma unroll
        for (int w=0;w<16;w++) acc += as[v][w]*xs[hc][w];
        h1s[hc][v] = acc;
    }
    __syncthreads();
    for (int idx=t; idx<4096; idx+=256){
        int v = idx & 15, hc = idx >> 4;
        float acc = 0.f;
        #pragma unroll
        for (int w=0;w<16;w++) acc += as[v][w]*h1s[hc][w];
        h2s[hc][v] = acc;
    }
    __syncthreads();
    int hc = t;
    #pragma unroll
    for (int w=0;w<16;w++){
        size_t row = (size_t)((n*16 + w)*4 + tt);
        amid[row*768 +       hc] = f2bf(xs[hc][w]);
        amid[row*768 + 256 + hc] = f2bf(h1s[hc][w]);
        amid[row*768 + 512 + hc] = f2bf(h2s[hc][w]);
    }
}

// ---------------- head ----------------
__global__ __launch_bounds__(256)
void k_z(const u16* __restrict__ h, u16* __restrict__ z)
{
    int bid = blockIdx.x, t = threadIdx.x;     // bid = n*16+c
    #pragma unroll
    for (int tc=0;tc<4;tc++)
        z[((size_t)bid*4 + tc)*HD + t] = f2bf(tanhf(bf2f(h[((size_t)bid*LSEQ + TT + tc)*HD + t])));
}

__global__ __launch_bounds__(256)
void k_head1p(const u16* __restrict__ z, const float* __restrict__ Wd1,
              float* __restrict__ d1p)
{
    __shared__ float zch[64][137];
    __shared__ float wt[16][137];
    int t = threadIdx.x;
    int col = t & 15, rgrp = t >> 4;
    int ob = blockIdx.x * 16;
    int kb = blockIdx.y;
    float acc[4] = {0.f,0.f,0.f,0.f};
    for (int kc=0; kc<1024; kc+=128){
        int base_k = kb*1024 + kc;
        #pragma unroll
        for (int jj=0; jj<16; jj++){
            int idx = t + jj*256;
            int n = idx >> 6, k2 = (idx & 63) << 1;
            u32 r = *(const u32*)&z[(size_t)n*16384 + base_k + k2];
            zch[n][k2] = lo16(r); zch[n][k2+1] = hi16(r);
        }
        #pragma unroll
        for (int jj=0; jj<2; jj++){
            int idx = t + jj*256;
            int r = idx >> 5, k4 = (idx & 31) << 2;
            float4 w4 = *(const float4*)&Wd1[(size_t)(ob + r)*16384 + base_k + k4];
            wt[r][k4] = w4.x; wt[r][k4+1] = w4.y; wt[r][k4+2] = w4.z; wt[r][k4+3] = w4.w;
        }
        __syncthreads();
        for (int k=0;k<128;k++){
            float wv = wt[col][k];
            #pragma unroll
            for (int u=0;u<4;u++) acc[u] += zch[rgrp + 16*u][k]*wv;
        }
        __syncthreads();
    }
    #pragma unroll
    for (int u=0;u<4;u++)
        d1p[(size_t)(kb*64 + rgrp + 16*u)*HD + ob + col] = acc[u];
}

__global__ __launch_bounds__(256)
void k_headf(const float* __restrict__ d1p, const float* __restrict__ bd1,
             const float* __restrict__ Wd2, const float* __restrict__ bd2,
             float* __restrict__ out)
{
    __shared__ float red[4];
    int n = blockIdx.x, c = threadIdx.x;
    float s = 0.f;
    #pragma unroll
    for (int kb=0; kb<16; kb++) s += d1p[(size_t)(kb*64 + n)*HD + c];
    float xx = s + bd1[c];
    float ge = 0.5f*xx*(1.f + erff(xx*0.70710678118654752f));
    float p = ge * Wd2[c];
    #pragma unroll
    for (int m=1;m<64;m<<=1) p += __shfl_xor(p, m, 64);
    if ((c & 63) == 0) red[c >> 6] = p;
    __syncthreads();
    if (c == 0) out[n] = red[0]+red[1]+red[2]+red[3] + bd2[0];
}

// ---------------- launch ----------------
extern "C" void kernel_launch(void* const* d_in, const int* in_sizes, int n_in,
                              void* d_out, int out_size, void* d_ws, size_t ws_size,
                              hipStream_t stream)
{
    const float* x    = (const float*)d_in[0];
    const float* Wfc  = (const float*)d_in[3];
    const float* bfc  = (const float*)d_in[4];
    const float* cls  = (const float*)d_in[5];
    const float* pos  = (const float*)d_in[6];
    const float* emb1 = (const float*)d_in[7];
    const float* emb2 = (const float*)d_in[8];
    const float* Wl1  = (const float*)d_in[9];
    const float* bl1  = (const float*)d_in[10];
    const float* Wl2  = (const float*)d_in[11];
    const float* bl2  = (const float*)d_in[12];
    const float* Wqkv = (const float*)d_in[13];
    const float* bqkv = (const float*)d_in[14];
    const float* Wo   = (const float*)d_in[15];
    const float* bo   = (const float*)d_in[16];
    const float* W1   = (const float*)d_in[17];
    const float* b1   = (const float*)d_in[18];
    const float* W2   = (const float*)d_in[19];
    const float* b2   = (const float*)d_in[20];
    const float* ln1g = (const float*)d_in[21];
    const float* ln1b = (const float*)d_in[22];
    const float* ln2g = (const float*)d_in[23];
    const float* ln2b = (const float*)d_in[24];
    const float* Wmlp = (const float*)d_in[25];
    const float* bmlp = (const float*)d_in[26];
    const float* Wd1  = (const float*)d_in[27];
    const float* bd1  = (const float*)d_in[28];
    const float* Wd2  = (const float*)d_in[29];
    const float* bd2  = (const float*)d_in[30];

    // dynamic chunk selection (2048 B/token)
    int NCH = 8;
    {
        const size_t fixed = 63145088 + (1<<20);
        if      (fixed + (size_t)MTOK    *2048 <= ws_size) NCH = 1;
        else if (fixed + (size_t)(MTOK/2)*2048 <= ws_size) NCH = 2;
        else if (fixed + (size_t)(MTOK/4)*2048 <= ws_size) NCH = 4;
    }
    const int RCH = MTOK / NCH;
    const int SCH = BSEQ / NCH;

    // workspace layout
    u16* h    = (u16*)d_ws;                    // 26,214,400 u16
    u16* buf  = h    + (size_t)MTOK*HD;        // RCH*1024  (qkv / ff1 / mixprop amid)
    u16* wq   = buf  + (size_t)RCH*1024;       //    786,432
    u16* wo   = wq   + (size_t)4*768*256;      //    262,144
    u16* w1   = wo   + (size_t)4*256*256;      //  1,048,576
    u16* w2   = w1   + (size_t)4*1024*256;     //  1,048,576
    u16* wmb  = w2   + (size_t)4*256*1024;     //    589,824
    u16* zb   = wmb  + (size_t)3*256*768;      //  1,048,576
    float* fp = (float*)(zb + (size_t)BSZ*16384);
    float* m1  = fp;
    float* m2  = m1 + CCH*HD;
    float* an  = m2 + CCH*HD;
    float* d1p = an + CCH*CCH;                 // 16*64*256

    // one-time weight prep
    k_cvt<<<512, 256, 0, stream>>>(Wqkv, wq, 4*768*256);
    k_cvt<<<256, 256, 0, stream>>>(Wo,   wo, 4*256*256);
    k_cvt<<<512, 256, 0, stream>>>(W1,   w1, 4*1024*256);
    k_cvt<<<512, 256, 0, stream>>>(W2,   w2, 4*256*1024);
    k_cvt<<<256, 256, 0, stream>>>(Wmlp, wmb, 3*256*768);

    k_embed<<<BSEQ, 256, 0, stream>>>(x, Wfc, bfc, cls, pos, h);
    k_graph_m<<<16, 256, 0, stream>>>(emb1, Wl1, bl1, m1);
    k_graph_m<<<16, 256, 0, stream>>>(emb2, Wl2, bl2, m2);
    k_graph_a<<<1, 256, 0, stream>>>(m1, m2, an);

    for (int l=0; l<NLAY; l++){
        if (l > 0){
            k_mixprep<<<BSZ*NCLS, 256, 0, stream>>>(h, an, buf);
            k_gemmA<<<dim3(256/128, 4096/128), 256, 0, stream>>>(
                buf, 768, wmb + (size_t)(l-1)*256*768, bmlp + (size_t)(l-1)*HD,
                h, HD, 768, 0, 1);
        }

        for (int c=0; c<NCH; c++){
            size_t row0 = (size_t)c * RCH;
            k_gemmA<<<dim3(768/128, RCH/128), 256, 0, stream>>>(
                h + row0*HD, HD, wq + (size_t)l*768*256, bqkv + (size_t)l*768,
                buf, 768, HD, 0, 0);
            k_attn<<<SCH*NHEAD/2, 256, 0, stream>>>(buf);
            // out-proj + residual + LN1 fused (reads q-slot of buf, lda=768)
            k_gemmC<<<RCH/64, 256, 0, stream>>>(
                buf, 768, HD, wo + (size_t)l*256*256, bo + (size_t)l*HD,
                h, ln1g + (size_t)l*HD, ln1b + (size_t)l*HD, row0);
            k_gemmA<<<dim3(1024/128, RCH/128), 256, 0, stream>>>(
                h + row0*HD, HD, w1 + (size_t)l*1024*256, b1 + (size_t)l*1024,
                buf, 1024, HD, 1, 0);
            // FF2 + residual + LN2 fused
            k_gemmC<<<RCH/64, 256, 0, stream>>>(
                buf, 1024, 1024, w2 + (size_t)l*256*1024, b2 + (size_t)l*HD,
                h, ln2g + (size_t)l*HD, ln2b + (size_t)l*HD, row0);
        }
    }

    k_z<<<BSZ*CCH, 256, 0, stream>>>(h, zb);
    k_head1p<<<dim3(16, 16), 256, 0, stream>>>(zb, Wd1, d1p);
    k_headf<<<BSZ, 256, 0, stream>>>(d1p, bd1, Wd2, bd2, (float*)d_out);
}

// Round 10
// 1974.470 us; speedup vs baseline: 2.0685x; 1.0072x over previous
//
#include <hip/hip_runtime.h>
#include <hip/hip_bf16.h>
#include <math.h>

typedef unsigned short u16;
typedef unsigned int   u32;
typedef __attribute__((ext_vector_type(8))) short short8;   // 8 bf16 = 4 VGPRs
typedef __attribute__((ext_vector_type(4))) float f32x4;

// ---- model dims ----
#define BSZ   64
#define TT    96
#define CCH   16
#define INDIM 16
#define HD    256
#define NHEAD 8
#define DHEAD 32
#define NCLS  4
#define LSEQ  100      // TT + NCLS
#define NLAY  4
#define EPSV  1e-5f
#define BSEQ  (BSZ*CCH)        // 1024 sequences
#define MTOK  (BSEQ*LSEQ)      // 102400 tokens

#if __has_builtin(__builtin_amdgcn_exp2f)
#define EXP2F __builtin_amdgcn_exp2f
#else
#define EXP2F exp2f
#endif

__device__ __forceinline__ float bf2f(u16 x){ return __uint_as_float(((u32)x)<<16); }
__device__ __forceinline__ u16 f2bf(float f){
    u32 u = __float_as_uint(f);
    u32 r = (u + 0x7fffu + ((u>>16)&1u)) >> 16;
    return (u16)r;
}
__device__ __forceinline__ float lo16(u32 r){ return __uint_as_float(r<<16); }
__device__ __forceinline__ float hi16(u32 r){ return __uint_as_float(r&0xffff0000u); }

// HW packed f32->bf16 (RNE), 1 instr per 2 elements
__device__ __forceinline__ u32 cvtpk(float lo, float hi){
    u32 r;
    asm("v_cvt_pk_bf16_f32 %0, %1, %2" : "=v"(r) : "v"(lo), "v"(hi));
    return r;
}

// async global->LDS, 16B per lane; LDS dest = (wave-uniform base) + lane*16
__device__ __forceinline__ void gload_lds16(const u16* g, u16* l){
    __builtin_amdgcn_global_load_lds(
        (const __attribute__((address_space(1))) unsigned int*)g,
        (__attribute__((address_space(3))) unsigned int*)l, 16, 0, 0);
}

// ---------------- f32 -> bf16 bulk convert ----------------
__global__ __launch_bounds__(256)
void k_cvt(const float* __restrict__ src, u16* __restrict__ dst, int n)
{
    for (int i = blockIdx.x*256 + threadIdx.x; i < n; i += gridDim.x*256)
        dst[i] = f2bf(src[i]);
}

// ---------------- embed ----------------
__global__ __launch_bounds__(256)
void k_embed(const float* __restrict__ x, const float* __restrict__ Wfc,
             const float* __restrict__ bfc, const float* __restrict__ cls,
             const float* __restrict__ pos, u16* __restrict__ h)
{
    int s = blockIdx.x;                // 0..1023 = n*16 + c
    int n = s >> 4, c = s & 15;
    int hc = threadIdx.x;
    float wr[INDIM];
    #pragma unroll
    for (int i=0;i<INDIM;i++) wr[i] = Wfc[hc*INDIM + i];
    float bb = bfc[hc];
    for (int l=0; l<TT; l++){
        const float* xr = x + (size_t)((n*TT + l)*CCH + c)*INDIM;
        float acc = bb;
        #pragma unroll
        for (int i=0;i<INDIM;i++) acc += xr[i]*wr[i];
        acc += pos[(size_t)(l*CCH + c)*HD + hc];
        h[((size_t)s*LSEQ + l)*HD + hc] = f2bf(acc);
    }
    #pragma unroll
    for (int l=TT; l<LSEQ; l++){
        float v = cls[(size_t)((l-TT)*CCH + c)*HD + hc]
                + pos[(size_t)(l*CCH + c)*HD + hc];
        h[((size_t)s*LSEQ + l)*HD + hc] = f2bf(v);
    }
}

// ---------------- graph constructor ----------------
__global__ __launch_bounds__(256)
void k_graph_m(const float* __restrict__ emb, const float* __restrict__ Wl,
               const float* __restrict__ bl, float* __restrict__ m)
{
    int r = blockIdx.x, o = threadIdx.x;
    __shared__ float e[HD];
    e[o] = emb[r*HD + o];
    __syncthreads();
    const float* w = Wl + (size_t)o*HD;
    float acc = bl[o];
    for (int k=0;k<HD;k++) acc += e[k]*w[k];
    m[r*HD + o] = tanhf(acc);
}

__global__ __launch_bounds__(256)
void k_graph_a(const float* __restrict__ m1, const float* __restrict__ m2,
               float* __restrict__ a)
{
    int t = threadIdx.x; int v = t >> 4, w = t & 15;
    __shared__ float adj[16][17];
    float s1=0.f, s2=0.f;
    for (int k=0;k<HD;k++){
        s1 += m1[v*HD+k]*m2[w*HD+k];
        s2 += m2[v*HD+k]*m1[w*HD+k];
    }
    float g = tanhf(s1 - s2); g = g > 0.f ? g : 0.f;
    adj[v][w] = g + (v==w ? 1.f : 0.f);
    __syncthreads();
    float rs = 0.f;
    #pragma unroll
    for (int j=0;j<16;j++) rs += adj[v][j];
    a[t] = adj[v][w] / rs;
}

// ---------------- MFMA GEMM, BK=64, counted-vmcnt 2-ahead pipeline ----------
__global__ __launch_bounds__(256)
void k_gemmA(const u16* __restrict__ A, int lda,
             const u16* __restrict__ W, const float* __restrict__ bias,
             u16* __restrict__ C, int ldc, int K, int relu, int scat)
{
    __shared__ u16 smem[32768];            // 64 KB union
    u16* As0 = smem;                       // [2][4096]
    u16* As1 = smem + 8192;                // [2][4096]
    u16* Ws0 = smem + 16384;               // [2][4096]
    u16* Ws1 = smem + 24576;               // [2][4096]

    int t = threadIdx.x;
    int lane = t & 63, w = t >> 6;
    int wm = (w & 1)*64, wn = (w >> 1)*64;
    int fr = lane & 15, quad = lane >> 4;

    // XCD-aware tile remap (bijective; all grids here are %8==0)
    int nwg = gridDim.x * gridDim.y;
    int bid = blockIdx.y * gridDim.x + blockIdx.x;
    int tile = bid;
    if (!(nwg & 7)){
        int cpx = nwg >> 3;
        tile = (bid & 7)*cpx + (bid >> 3);
    }
    int bx = tile % gridDim.x, by = tile / gridDim.x;
    size_t mb = (size_t)by * 128;
    int nb = bx * 128;

    int srow = lane >> 2;
    int sslot = lane & 3;

    f32x4 acc[4][4] = {};

    auto STAGE = [&](int bb, int k0){     // 8 gloads per thread
        #pragma unroll
        for (int i=0;i<2;i++){
            int r = w*32 + i*16 + srow;
            int cw = sslot ^ ((r>>1)&3);
            gload_lds16(&A[(mb + r)*(size_t)lda + k0      + cw*8], &As0[bb*4096 + (w*32 + i*16)*32]);
            gload_lds16(&A[(mb + r)*(size_t)lda + k0 + 32 + cw*8], &As1[bb*4096 + (w*32 + i*16)*32]);
            gload_lds16(&W[(size_t)(nb + r)*K   + k0      + cw*8], &Ws0[bb*4096 + (w*32 + i*16)*32]);
            gload_lds16(&W[(size_t)(nb + r)*K   + k0 + 32 + cw*8], &Ws1[bb*4096 + (w*32 + i*16)*32]);
        }
    };
    auto COMPUTE = [&](int bb){
        short8 af0[4], af1[4], bf0[4], bf1[4];
        #pragma unroll
        for (int mt=0; mt<4; mt++){
            int r = wm + mt*16 + fr;
            int sw = (quad ^ ((r>>1)&3)) << 3;
            af0[mt] = *(const short8*)&As0[bb*4096 + r*32 + sw];
            af1[mt] = *(const short8*)&As1[bb*4096 + r*32 + sw];
        }
        #pragma unroll
        for (int nt=0; nt<4; nt++){
            int r = wn + nt*16 + fr;
            int sw = (quad ^ ((r>>1)&3)) << 3;
            bf0[nt] = *(const short8*)&Ws0[bb*4096 + r*32 + sw];
            bf1[nt] = *(const short8*)&Ws1[bb*4096 + r*32 + sw];
        }
        #pragma unroll
        for (int mt=0; mt<4; mt++)
            #pragma unroll
            for (int nt=0; nt<4; nt++){
                acc[mt][nt] = __builtin_amdgcn_mfma_f32_16x16x32_bf16(
                    af0[mt], bf0[nt], acc[mt][nt], 0, 0, 0);
                acc[mt][nt] = __builtin_amdgcn_mfma_f32_16x16x32_bf16(
                    af1[mt], bf1[nt], acc[mt][nt], 0, 0, 0);
            }
    };

    const int nst = K >> 6;
    STAGE(0, 0);
    if (nst > 1) STAGE(1, 64);
    int b = 0;
    for (int ts = 0; ts < nst; ++ts){
        if (ts + 1 < nst) asm volatile("s_waitcnt vmcnt(8)" ::: "memory");
        else              asm volatile("s_waitcnt vmcnt(0)" ::: "memory");
        __builtin_amdgcn_s_barrier();
        COMPUTE(b);
        __builtin_amdgcn_s_barrier();
        if (ts + 2 < nst) STAGE(b, (ts+2) << 6);
        b ^= 1;
    }

    // ---- epilogue: bias(+relu) -> LDS tile -> coalesced dwordx4 stores ----
    float bb4[4];
    #pragma unroll
    for (int nt=0; nt<4; nt++) bb4[nt] = bias[nb + wn + nt*16 + fr];
    u16* Ct = smem;                        // 128x128 u16
    #pragma unroll
    for (int mt=0; mt<4; mt++){
        int rw = wm + mt*16 + quad*4;
        #pragma unroll
        for (int nt=0; nt<4; nt++){
            int col = wn + nt*16 + fr;
            float v0 = acc[mt][nt][0] + bb4[nt];
            float v1 = acc[mt][nt][1] + bb4[nt];
            float v2 = acc[mt][nt][2] + bb4[nt];
            float v3 = acc[mt][nt][3] + bb4[nt];
            if (relu){
                v0 = v0 > 0.f ? v0 : 0.f;  v1 = v1 > 0.f ? v1 : 0.f;
                v2 = v2 > 0.f ? v2 : 0.f;  v3 = v3 > 0.f ? v3 : 0.f;
            }
            u32 p01 = cvtpk(v0, v1), p23 = cvtpk(v2, v3);
            Ct[(rw+0)*128 + col] = (u16)p01;
            Ct[(rw+1)*128 + col] = (u16)(p01 >> 16);
            Ct[(rw+2)*128 + col] = (u16)p23;
            Ct[(rw+3)*128 + col] = (u16)(p23 >> 16);
        }
    }
    __syncthreads();
    #pragma unroll
    for (int it=0; it<8; ++it){
        int row = it*16 + (t>>4);
        int seg = t & 15;
        size_t rg = mb + row;
        if (scat) rg = (rg >> 2)*LSEQ + TT + (rg & 3);
        *(short8*)&C[rg*(size_t)ldc + nb + seg*8] = *(const short8*)&Ct[row*128 + seg*8];
    }
}

// ------- MFMA GEMM (N=256) + bias + residual + LayerNorm fused, in-place h -------
__global__ __launch_bounds__(256)
void k_gemmC(const u16* __restrict__ A, int lda, int K,
             const u16* __restrict__ W, const float* __restrict__ bias,
             u16* __restrict__ h, const float* __restrict__ gam,
             const float* __restrict__ bet, size_t row0)
{
    __shared__ u16 smem[40960];            // 80 KB union
    u16* As0 = smem;                       // [2][2048]
    u16* As1 = smem + 4096;                // [2][2048]
    u16* Ws0 = smem + 8192;                // [2][8192]
    u16* Ws1 = smem + 24576;               // [2][8192]

    int t = threadIdx.x;
    int lane = t & 63, w = t >> 6;
    int fr = lane & 15, quad = lane >> 4;
    size_t mb = (size_t)blockIdx.x * 64;
    int srow = lane >> 2, sslot = lane & 3;

    f32x4 acc[4][4] = {};

    auto STAGE = [&](int bb, int k0){     // 10 gloads per thread
        {
            int r = w*16 + srow;
            int cw = sslot ^ ((r>>1)&3);
            gload_lds16(&A[(mb + r)*(size_t)lda + k0      + cw*8], &As0[bb*2048 + (w*16)*32]);
            gload_lds16(&A[(mb + r)*(size_t)lda + k0 + 32 + cw*8], &As1[bb*2048 + (w*16)*32]);
        }
        #pragma unroll
        for (int i=0;i<4;i++){
            int r = w*64 + i*16 + srow;
            int cw = sslot ^ ((r>>1)&3);
            gload_lds16(&W[(size_t)r*K + k0      + cw*8], &Ws0[bb*8192 + (w*64 + i*16)*32]);
            gload_lds16(&W[(size_t)r*K + k0 + 32 + cw*8], &Ws1[bb*8192 + (w*64 + i*16)*32]);
        }
    };
    auto COMPUTE = [&](int bb){
        short8 af0[4], af1[4], bf0[4], bf1[4];
        #pragma unroll
        for (int mt=0; mt<4; mt++){
            int ra = mt*16 + fr;
            int swa = (quad ^ ((ra>>1)&3)) << 3;
            af0[mt] = *(const short8*)&As0[bb*2048 + ra*32 + swa];
            af1[mt] = *(const short8*)&As1[bb*2048 + ra*32 + swa];
        }
        #pragma unroll
        for (int nt=0; nt<4; nt++){
            int rb = w*64 + nt*16 + fr;
            int swb = (quad ^ ((rb>>1)&3)) << 3;
            bf0[nt] = *(const short8*)&Ws0[bb*8192 + rb*32 + swb];
            bf1[nt] = *(const short8*)&Ws1[bb*8192 + rb*32 + swb];
        }
        #pragma unroll
        for (int mt=0; mt<4; mt++)
            #pragma unroll
            for (int nt=0; nt<4; nt++){
                acc[mt][nt] = __builtin_amdgcn_mfma_f32_16x16x32_bf16(
                    af0[mt], bf0[nt], acc[mt][nt], 0, 0, 0);
                acc[mt][nt] = __builtin_amdgcn_mfma_f32_16x16x32_bf16(
                    af1[mt], bf1[nt], acc[mt][nt], 0, 0, 0);
            }
    };

    const int nst = K >> 6;
    STAGE(0, 0);
    if (nst > 1) STAGE(1, 64);
    int b = 0;
    for (int ts = 0; ts < nst; ++ts){
        if (ts + 1 < nst) asm volatile("s_waitcnt vmcnt(10)" ::: "memory");
        else              asm volatile("s_waitcnt vmcnt(0)"  ::: "memory");
        __builtin_amdgcn_s_barrier();
        COMPUTE(b);
        __builtin_amdgcn_s_barrier();
        if (ts + 2 < nst) STAGE(b, (ts+2) << 6);
        b ^= 1;
    }

    // ---- epilogue: v = acc + bias + residual ----
    float bb4[4], gg[4], be[4];
    #pragma unroll
    for (int nt=0; nt<4; nt++){
        int col = w*64 + nt*16 + fr;
        bb4[nt] = bias[col]; gg[nt] = gam[col]; be[nt] = bet[col];
    }
    #pragma unroll
    for (int mt=0; mt<4; mt++){
        #pragma unroll
        for (int r=0; r<4; r++){
            size_t row = row0 + mb + mt*16 + quad*4 + r;
            #pragma unroll
            for (int nt=0; nt<4; nt++)
                acc[mt][nt][r] += bb4[nt] + bf2f(h[row*HD + w*64 + nt*16 + fr]);
        }
    }
    __syncthreads();
    float* red  = (float*)smem;            // 256 f32
    float* red2 = (float*)(smem + 512);    // 256 f32
    float ps[4][4];
    #pragma unroll
    for (int mt=0; mt<4; mt++)
        #pragma unroll
        for (int r=0; r<4; r++){
            float s = acc[mt][0][r] + acc[mt][1][r] + acc[mt][2][r] + acc[mt][3][r];
            s += __shfl_xor(s,1,64); s += __shfl_xor(s,2,64);
            s += __shfl_xor(s,4,64); s += __shfl_xor(s,8,64);
            ps[mt][r] = s;
        }
    if (fr == 0){
        #pragma unroll
        for (int mt=0; mt<4; mt++)
            #pragma unroll
            for (int r=0; r<4; r++)
                red[w*64 + mt*16 + quad*4 + r] = ps[mt][r];
    }
    __syncthreads();
    float mean[4][4];
    #pragma unroll
    for (int mt=0; mt<4; mt++)
        #pragma unroll
        for (int r=0; r<4; r++){
            int rl = mt*16 + quad*4 + r;
            mean[mt][r] = (red[rl] + red[64+rl] + red[128+rl] + red[192+rl]) * (1.f/256.f);
            float s = 0.f;
            #pragma unroll
            for (int nt=0; nt<4; nt++){ float d = acc[mt][nt][r] - mean[mt][r]; s += d*d; }
            s += __shfl_xor(s,1,64); s += __shfl_xor(s,2,64);
            s += __shfl_xor(s,4,64); s += __shfl_xor(s,8,64);
            ps[mt][r] = s;
        }
    if (fr == 0){
        #pragma unroll
        for (int mt=0; mt<4; mt++)
            #pragma unroll
            for (int r=0; r<4; r++)
                red2[w*64 + mt*16 + quad*4 + r] = ps[mt][r];
    }
    __syncthreads();
    // ---- normalize -> LDS tile -> coalesced stores ----
    u16* Ct = smem + 8192;                 // 64x256 u16
    #pragma unroll
    for (int mt=0; mt<4; mt++)
        #pragma unroll
        for (int r=0; r<4; r++){
            int rl = mt*16 + quad*4 + r;
            float inv = rsqrtf((red2[rl] + red2[64+rl] + red2[128+rl] + red2[192+rl])
                               * (1.f/256.f) + EPSV);
            float o0 = (acc[mt][0][r] - mean[mt][r]) * inv * gg[0] + be[0];
            float o1 = (acc[mt][1][r] - mean[mt][r]) * inv * gg[1] + be[1];
            float o2 = (acc[mt][2][r] - mean[mt][r]) * inv * gg[2] + be[2];
            float o3 = (acc[mt][3][r] - mean[mt][r]) * inv * gg[3] + be[3];
            u32 p01 = cvtpk(o0, o1), p23 = cvtpk(o2, o3);
            Ct[rl*256 + w*64 +  0 + fr] = (u16)p01;
            Ct[rl*256 + w*64 + 16 + fr] = (u16)(p01 >> 16);
            Ct[rl*256 + w*64 + 32 + fr] = (u16)p23;
            Ct[rl*256 + w*64 + 48 + fr] = (u16)(p23 >> 16);
        }
    __syncthreads();
    #pragma unroll
    for (int it=0; it<8; ++it){
        int row = it*8 + (t>>5);
        int seg = t & 31;
        *(short8*)&h[(row0 + mb + row)*HD + seg*8] = *(const short8*)&Ct[row*256 + seg*8];
    }
}

// ---------------- MFMA attention, 8-wave occupancy variant ----------------
// r10: 512 threads = 8 waves (4 per head); strip-groups {6},{0,5},{1,4},{2,3}
// are 7 S-units each (balanced). Per-wave private P buffers sized per group
// (2048/1536/1536/1024 u16) packed into 48 KB LDS -> 3 blocks/CU = 24 waves/CU
// (vs 8 before) on this latency-bound kernel. Per-strip math unchanged from r7.
#define KS_STR 40
#define VT_STR 136
__global__ __launch_bounds__(512)
void k_attn(u16* __restrict__ qkv)
{
    __shared__ u16 smem[24576];   // 48 KB. stage: Ks 2x4480 @0 | Vt 2x4352 @8960 (dead after prefetch)
                                  // strips: Ph [0,12288) | Pv [12288,24576), per (head,wsgrp) offsets
    int t = threadIdx.x;
    int w = t >> 6, lane = t & 63;
    int fr = lane & 15, quad = lane >> 4;
    int p = t >> 8, t2 = t & 255;          // staging half (one per head)
    u16* Ks = smem + p*4480;
    u16* Vt = smem + 8960 + p*4352;

    {
        int gp = blockIdx.x*2 + p;
        size_t base = (size_t)(gp >> 3)*LSEQ*768 + (gp & 7)*32;
        for (int idx = t2; idx < 1792; idx += 256){
            int key = idx >> 4, d2 = (idx & 15) << 1;
            u32 kv = (key < LSEQ) ? *(const u32*)&qkv[base + (size_t)key*768 + 256 + d2] : 0u;
            *(u32*)&Ks[key*KS_STR + d2] = kv;
        }
        // key-major V transpose staging: lanes stride-1 in key -> conflict-free writes
        for (int idx = t2; idx < 2048; idx += 256){
            int key = idx & 127, d2 = (idx >> 7) << 1;
            u32 vv = (key < LSEQ) ? *(const u32*)&qkv[base + (size_t)key*768 + 512 + d2] : 0u;
            Vt[ d2   *VT_STR + key] = (u16)(vv & 0xffffu);
            Vt[(d2+1)*VT_STR + key] = (u16)(vv >> 16);
        }
    }
    __syncthreads();

    int hp = w >> 2;              // head within block (0,1)
    int ws = w & 3;               // strip group (0..3)
    int gp = blockIdx.x*2 + hp;
    size_t base = (size_t)(gp >> 3)*LSEQ*768 + (gp & 7)*32;
    u16* Ksw = smem + hp*4480;
    u16* Vtw = smem + 8960 + hp*4352;

    short8 kf[7];
    #pragma unroll
    for (int nt=0; nt<7; nt++)
        kf[nt] = *(const short8*)&Ksw[(nt*16 + fr)*KS_STR + quad*8];
    short8 vfr[4][2];
    #pragma unroll
    for (int ks=0; ks<4; ks++)
        #pragma unroll
        for (int nt=0; nt<2; nt++)
            vfr[ks][nt] = *(const short8*)&Vtw[(nt*16 + fr)*VT_STR + ks*32 + quad*8];

    // strip groups: {6}, {0,5}, {1,4}, {2,3} — 7 S-units each
    int smask = (ws==0) ? 0x40 : (ws==1) ? 0x21 : (ws==2) ? 0x12 : 0x0C;
    // prefetch q fragments for this wave's strips (before any output store can alias)
    short8 qfs[7];
    #pragma unroll
    for (int st=0; st<7; ++st){
        if (!((smask >> st) & 1)) continue;
        int q = st*16 + fr;
        short8 z = {};
        qfs[st] = (q < LSEQ) ? *(const short8*)&qkv[base + (size_t)q*768 + quad*8] : z;
    }
    __syncthreads();   // all waves done reading Ks/Vt before Ph/Pv overlay reuse

    // per-(head, strip-group) P buffers: sizes 2048/1536/1536/1024 u16
    int pref = ws ? (1536*ws + 512) : 0;
    u16* Ph = smem + hp*6144 + pref;            // [0, 12288)
    u16* Pv = smem + 12288 + hp*6144 + pref;    // [12288, 24576)

    const float cs = 0.17677669529663687f * 1.4426950408889634f;  // (1/sqrt32)*log2(e)
    #pragma unroll
    for (int st = 0; st < 7; ++st){
        if (!((smask >> st) & 1)) continue;
        const int ntile = (st == 6) ? 7 : (st + 1);
        const int nks   = (st == 6) ? 4 : (st/2 + 1);
        f32x4 S[7];
        #pragma unroll
        for (int nt=0; nt<7; nt++){
            if (nt >= ntile) continue;
            f32x4 z = {};
            S[nt] = __builtin_amdgcn_mfma_f32_16x16x32_bf16(qfs[st], kf[nt], z, 0,0,0);
        }
        // scale (in log2 domain); mask ONLY the last tile (full tiles causal-valid)
        float mx[4] = {-1e30f,-1e30f,-1e30f,-1e30f};
        #pragma unroll
        for (int nt=0;nt<7;nt++){
            if (nt >= ntile) continue;
            #pragma unroll
            for (int r=0;r<4;r++){
                float s = S[nt][r]*cs;
                if (nt == ntile-1){
                    int qr = st*16 + quad*4 + r;
                    int jmax = (qr < TT) ? qr : (LSEQ-1);
                    s = ((nt*16 + fr) <= jmax) ? s : -1e30f;
                }
                S[nt][r] = s;
                mx[r] = fmaxf(mx[r], s);
            }
        }
        #pragma unroll
        for (int r=0;r<4;r++){
            #pragma unroll
            for (int m=1;m<16;m<<=1) mx[r] = fmaxf(mx[r], __shfl_xor(mx[r], m, 64));
        }
        float l4[4] = {0.f,0.f,0.f,0.f};
        #pragma unroll
        for (int r=0;r<4;r++){
            #pragma unroll
            for (int nt=0;nt<7;nt++){
                if (nt >= ntile) continue;
                float pv = EXP2F(S[nt][r] - mx[r]);
                S[nt][r] = pv;
                l4[r] += pv;
            }
        }
        #pragma unroll
        for (int r=0;r<4;r++){
            #pragma unroll
            for (int m=1;m<16;m<<=1) l4[r] += __shfl_xor(l4[r], m, 64);
        }
        // WAR fence: this wave's previous strip's Ph/Pv reads must complete (buffers private)
        asm volatile("s_waitcnt lgkmcnt(0)" ::: "memory");
        // write P_hi + P_lo via packed cvt; panel layout [ks][16 rows][32 k], XOR swizzle
        #pragma unroll
        for (int nt=0;nt<7;nt++){
            if (nt >= ntile) continue;
            u32 h01 = cvtpk(S[nt][0], S[nt][1]);
            u32 h23 = cvtpk(S[nt][2], S[nt][3]);
            float l0 = S[nt][0] - lo16(h01);
            float l1 = S[nt][1] - hi16(h01);
            float l2 = S[nt][2] - lo16(h23);
            float l3 = S[nt][3] - hi16(h23);
            u32 g01 = cvtpk(l0, l1);
            u32 g23 = cvtpk(l2, l3);
            u16 hv[4] = {(u16)h01, (u16)(h01>>16), (u16)h23, (u16)(h23>>16)};
            u16 lv[4] = {(u16)g01, (u16)(g01>>16), (u16)g23, (u16)(g23>>16)};
            #pragma unroll
            for (int r=0;r<4;r++){
                int row = quad*4 + r;
                int a = (nt>>1)*512 + row*32 + ((((nt&1)<<4) + fr) ^ (((row>>1)&3)<<3));
                Ph[a] = hv[r];
                Pv[a] = lv[r];
            }
        }
        if (ntile*16 < nks*32){
            #pragma unroll
            for (int r=0;r<4;r++){
                int row = quad*4 + r;
                int a = (ntile>>1)*512 + row*32 + ((((ntile&1)<<4) + fr) ^ (((row>>1)&3)<<3));
                Ph[a] = 0;
                Pv[a] = 0;
            }
        }
        asm volatile("s_waitcnt lgkmcnt(0)" ::: "memory");
        f32x4 D[2] = {};
        #pragma unroll
        for (int ks=0; ks<4; ks++){
            if (ks >= nks) continue;
            int a = ks*512 + fr*32 + ((quad ^ ((fr>>1)&3)) << 3);
            short8 ph = *(const short8*)&Ph[a];
            short8 pl = *(const short8*)&Pv[a];
            #pragma unroll
            for (int nt=0; nt<2; nt++){
                D[nt] = __builtin_amdgcn_mfma_f32_16x16x32_bf16(ph, vfr[ks][nt], D[nt], 0,0,0);
                D[nt] = __builtin_amdgcn_mfma_f32_16x16x32_bf16(pl, vfr[ks][nt], D[nt], 0,0,0);
            }
        }
        #pragma unroll
        for (int r=0;r<4;r++){
            int qr = st*16 + quad*4 + r;
            if (qr < LSEQ){
                float inv = 1.f / l4[r];
                u32 o = cvtpk(D[0][r]*inv, D[1][r]*inv);
                qkv[base + (size_t)qr*768 +      fr] = (u16)o;
                qkv[base + (size_t)qr*768 + 16 + fr] = (u16)(o >> 16);
            }
        }
        // no trailing drain: next strip's WAR fence orders LDS; global rows disjoint
    }
}

// ---------------- mixprop prep ----------------
__global__ __launch_bounds__(256)
void k_mixprep(const u16* __restrict__ h, const float* __restrict__ a,
               u16* __restrict__ amid)
{
    int n = blockIdx.x >> 2, tt = blockIdx.x & 3;
    __shared__ float xs[256][17], h1s[256][17], h2s[256][17];
    __shared__ float as[16][17];
    int t = threadIdx.x;
    as[t>>4][t&15] = a[t];
    for (int idx=t; idx<4096; idx+=256){
        int w = idx >> 8, hc = idx & 255;
        xs[hc][w] = bf2f(h[((size_t)(n*16 + w)*LSEQ + TT + tt)*HD + hc]);
    }
    __syncthreads();
    for (int idx=t; idx<4096; idx+=256){
        int v = idx & 15, hc = idx >> 4;
        float acc = 0.f;
        #pragma unroll
        for (int w=0;w<16;w++) acc += as[v][w]*xs[hc][w];
        h1s[hc][v] = acc;
    }
    __syncthreads();
    for (int idx=t; idx<4096; idx+=256){
        int v = idx & 15, hc = idx >> 4;
        float acc = 0.f;
        #pragma unroll
        for (int w=0;w<16;w++) acc += as[v][w]*h1s[hc][w];
        h2s[hc][v] = acc;
    }
    __syncthreads();
    int hc = t;
    #pragma unroll
    for (int w=0;w<16;w++){
        size_t row = (size_t)((n*16 + w)*4 + tt);
        amid[row*768 +       hc] = f2bf(xs[hc][w]);
        amid[row*768 + 256 + hc] = f2bf(h1s[hc][w]);
        amid[row*768 + 512 + hc] = f2bf(h2s[hc][w]);
    }
}

// ---------------- head ----------------
__global__ __launch_bounds__(256)
void k_z(const u16* __restrict__ h, u16* __restrict__ z)
{
    int bid = blockIdx.x, t = threadIdx.x;     // bid = n*16+c
    #pragma unroll
    for (int tc=0;tc<4;tc++)
        z[((size_t)bid*4 + tc)*HD + t] = f2bf(tanhf(bf2f(h[((size_t)bid*LSEQ + TT + tc)*HD + t])));
}

__global__ __launch_bounds__(256)
void k_head1p(const u16* __restrict__ z, const float* __restrict__ Wd1,
              float* __restrict__ d1p)
{
    __shared__ float zch[64][137];
    __shared__ float wt[16][137];
    int t = threadIdx.x;
    int col = t & 15, rgrp = t >> 4;
    int ob = blockIdx.x * 16;
    int kb = blockIdx.y;
    float acc[4] = {0.f,0.f,0.f,0.f};
    for (int kc=0; kc<1024; kc+=128){
        int base_k = kb*1024 + kc;
        #pragma unroll
        for (int jj=0; jj<16; jj++){
            int idx = t + jj*256;
            int n = idx >> 6, k2 = (idx & 63) << 1;
            u32 r = *(const u32*)&z[(size_t)n*16384 + base_k + k2];
            zch[n][k2] = lo16(r); zch[n][k2+1] = hi16(r);
        }
        #pragma unroll
        for (int jj=0; jj<2; jj++){
            int idx = t + jj*256;
            int r = idx >> 5, k4 = (idx & 31) << 2;
            float4 w4 = *(const float4*)&Wd1[(size_t)(ob + r)*16384 + base_k + k4];
            wt[r][k4] = w4.x; wt[r][k4+1] = w4.y; wt[r][k4+2] = w4.z; wt[r][k4+3] = w4.w;
        }
        __syncthreads();
        for (int k=0;k<128;k++){
            float wv = wt[col][k];
            #pragma unroll
            for (int u=0;u<4;u++) acc[u] += zch[rgrp + 16*u][k]*wv;
        }
        __syncthreads();
    }
    #pragma unroll
    for (int u=0;u<4;u++)
        d1p[(size_t)(kb*64 + rgrp + 16*u)*HD + ob + col] = acc[u];
}

__global__ __launch_bounds__(256)
void k_headf(const float* __restrict__ d1p, const float* __restrict__ bd1,
             const float* __restrict__ Wd2, const float* __restrict__ bd2,
             float* __restrict__ out)
{
    __shared__ float red[4];
    int n = blockIdx.x, c = threadIdx.x;
    float s = 0.f;
    #pragma unroll
    for (int kb=0; kb<16; kb++) s += d1p[(size_t)(kb*64 + n)*HD + c];
    float xx = s + bd1[c];
    float ge = 0.5f*xx*(1.f + erff(xx*0.70710678118654752f));
    float p = ge * Wd2[c];
    #pragma unroll
    for (int m=1;m<64;m<<=1) p += __shfl_xor(p, m, 64);
    if ((c & 63) == 0) red[c >> 6] = p;
    __syncthreads();
    if (c == 0) out[n] = red[0]+red[1]+red[2]+red[3] + bd2[0];
}

// ---------------- launch ----------------
extern "C" void kernel_launch(void* const* d_in, const int* in_sizes, int n_in,
                              void* d_out, int out_size, void* d_ws, size_t ws_size,
                              hipStream_t stream)
{
    const float* x    = (const float*)d_in[0];
    const float* Wfc  = (const float*)d_in[3];
    const float* bfc  = (const float*)d_in[4];
    const float* cls  = (const float*)d_in[5];
    const float* pos  = (const float*)d_in[6];
    const float* emb1 = (const float*)d_in[7];
    const float* emb2 = (const float*)d_in[8];
    const float* Wl1  = (const float*)d_in[9];
    const float* bl1  = (const float*)d_in[10];
    const float* Wl2  = (const float*)d_in[11];
    const float* bl2  = (const float*)d_in[12];
    const float* Wqkv = (const float*)d_in[13];
    const float* bqkv = (const float*)d_in[14];
    const float* Wo   = (const float*)d_in[15];
    const float* bo   = (const float*)d_in[16];
    const float* W1   = (const float*)d_in[17];
    const float* b1   = (const float*)d_in[18];
    const float* W2   = (const float*)d_in[19];
    const float* b2   = (const float*)d_in[20];
    const float* ln1g = (const float*)d_in[21];
    const float* ln1b = (const float*)d_in[22];
    const float* ln2g = (const float*)d_in[23];
    const float* ln2b = (const float*)d_in[24];
    const float* Wmlp = (const float*)d_in[25];
    const float* bmlp = (const float*)d_in[26];
    const float* Wd1  = (const float*)d_in[27];
    const float* bd1  = (const float*)d_in[28];
    const float* Wd2  = (const float*)d_in[29];
    const float* bd2  = (const float*)d_in[30];

    // dynamic chunk selection (2048 B/token)
    int NCH = 8;
    {
        const size_t fixed = 63145088 + (1<<20);
        if      (fixed + (size_t)MTOK    *2048 <= ws_size) NCH = 1;
        else if (fixed + (size_t)(MTOK/2)*2048 <= ws_size) NCH = 2;
        else if (fixed + (size_t)(MTOK/4)*2048 <= ws_size) NCH = 4;
    }
    const int RCH = MTOK / NCH;
    const int SCH = BSEQ / NCH;

    // workspace layout
    u16* h    = (u16*)d_ws;                    // 26,214,400 u16
    u16* buf  = h    + (size_t)MTOK*HD;        // RCH*1024  (qkv / ff1 / mixprop amid)
    u16* wq   = buf  + (size_t)RCH*1024;       //    786,432
    u16* wo   = wq   + (size_t)4*768*256;      //    262,144
    u16* w1   = wo   + (size_t)4*256*256;      //  1,048,576
    u16* w2   = w1   + (size_t)4*1024*256;     //  1,048,576
    u16* wmb  = w2   + (size_t)4*256*1024;     //    589,824
    u16* zb   = wmb  + (size_t)3*256*768;      //  1,048,576
    float* fp = (float*)(zb + (size_t)BSZ*16384);
    float* m1  = fp;
    float* m2  = m1 + CCH*HD;
    float* an  = m2 + CCH*HD;
    float* d1p = an + CCH*CCH;                 // 16*64*256

    // one-time weight prep
    k_cvt<<<512, 256, 0, stream>>>(Wqkv, wq, 4*768*256);
    k_cvt<<<256, 256, 0, stream>>>(Wo,   wo, 4*256*256);
    k_cvt<<<512, 256, 0, stream>>>(W1,   w1, 4*1024*256);
    k_cvt<<<512, 256, 0, stream>>>(W2,   w2, 4*256*1024);
    k_cvt<<<256, 256, 0, stream>>>(Wmlp, wmb, 3*256*768);

    k_embed<<<BSEQ, 256, 0, stream>>>(x, Wfc, bfc, cls, pos, h);
    k_graph_m<<<16, 256, 0, stream>>>(emb1, Wl1, bl1, m1);
    k_graph_m<<<16, 256, 0, stream>>>(emb2, Wl2, bl2, m2);
    k_graph_a<<<1, 256, 0, stream>>>(m1, m2, an);

    for (int l=0; l<NLAY; l++){
        if (l > 0){
            k_mixprep<<<BSZ*NCLS, 256, 0, stream>>>(h, an, buf);
            k_gemmA<<<dim3(256/128, 4096/128), 256, 0, stream>>>(
                buf, 768, wmb + (size_t)(l-1)*256*768, bmlp + (size_t)(l-1)*HD,
                h, HD, 768, 0, 1);
        }

        for (int c=0; c<NCH; c++){
            size_t row0 = (size_t)c * RCH;
            k_gemmA<<<dim3(768/128, RCH/128), 256, 0, stream>>>(
                h + row0*HD, HD, wq + (size_t)l*768*256, bqkv + (size_t)l*768,
                buf, 768, HD, 0, 0);
            k_attn<<<SCH*NHEAD/2, 512, 0, stream>>>(buf);
            // out-proj + residual + LN1 fused (reads q-slot of buf, lda=768)
            k_gemmC<<<RCH/64, 256, 0, stream>>>(
                buf, 768, HD, wo + (size_t)l*256*256, bo + (size_t)l*HD,
                h, ln1g + (size_t)l*HD, ln1b + (size_t)l*HD, row0);
            k_gemmA<<<dim3(1024/128, RCH/128), 256, 0, stream>>>(
                h + row0*HD, HD, w1 + (size_t)l*1024*256, b1 + (size_t)l*1024,
                buf, 1024, HD, 1, 0);
            // FF2 + residual + LN2 fused
            k_gemmC<<<RCH/64, 256, 0, stream>>>(
                buf, 1024, 1024, w2 + (size_t)l*256*1024, b2 + (size_t)l*HD,
                h, ln2g + (size_t)l*HD, ln2b + (size_t)l*HD, row0);
        }
    }

    k_z<<<BSZ*CCH, 256, 0, stream>>>(h, zb);
    k_head1p<<<dim3(16, 16), 256, 0, stream>>>(zb, Wd1, d1p);
    k_headf<<<BSZ, 256, 0, stream>>>(d1p, bd1, Wd2, bd2, (float*)d_out);
}

// Round 12
// 1943.657 us; speedup vs baseline: 2.1013x; 1.0159x over previous
//
#include <hip/hip_runtime.h>
#include <hip/hip_bf16.h>
#include <math.h>

typedef unsigned short u16;
typedef unsigned int   u32;
typedef __attribute__((ext_vector_type(8))) short short8;   // 8 bf16 = 4 VGPRs
typedef __attribute__((ext_vector_type(4))) float f32x4;

// ---- model dims ----
#define BSZ   64
#define TT    96
#define CCH   16
#define INDIM 16
#define HD    256
#define NHEAD 8
#define DHEAD 32
#define NCLS  4
#define LSEQ  100      // TT + NCLS
#define NLAY  4
#define EPSV  1e-5f
#define BSEQ  (BSZ*CCH)        // 1024 sequences
#define MTOK  (BSEQ*LSEQ)      // 102400 tokens

#if __has_builtin(__builtin_amdgcn_exp2f)
#define EXP2F __builtin_amdgcn_exp2f
#else
#define EXP2F exp2f
#endif

__device__ __forceinline__ float bf2f(u16 x){ return __uint_as_float(((u32)x)<<16); }
__device__ __forceinline__ u16 f2bf(float f){
    u32 u = __float_as_uint(f);
    u32 r = (u + 0x7fffu + ((u>>16)&1u)) >> 16;
    return (u16)r;
}
__device__ __forceinline__ float lo16(u32 r){ return __uint_as_float(r<<16); }
__device__ __forceinline__ float hi16(u32 r){ return __uint_as_float(r&0xffff0000u); }

// HW packed f32->bf16 (RNE), 1 instr per 2 elements
__device__ __forceinline__ u32 cvtpk(float lo, float hi){
    u32 r;
    asm("v_cvt_pk_bf16_f32 %0, %1, %2" : "=v"(r) : "v"(lo), "v"(hi));
    return r;
}

// async global->LDS, 16B per lane; LDS dest = (wave-uniform base) + lane*16
__device__ __forceinline__ void gload_lds16(const u16* g, u16* l){
    __builtin_amdgcn_global_load_lds(
        (const __attribute__((address_space(1))) unsigned int*)g,
        (__attribute__((address_space(3))) unsigned int*)l, 16, 0, 0);
}

// ---------------- f32 -> bf16 bulk convert ----------------
__global__ __launch_bounds__(256)
void k_cvt(const float* __restrict__ src, u16* __restrict__ dst, int n)
{
    for (int i = blockIdx.x*256 + threadIdx.x; i < n; i += gridDim.x*256)
        dst[i] = f2bf(src[i]);
}

// ---------------- embed ----------------
__global__ __launch_bounds__(256)
void k_embed(const float* __restrict__ x, const float* __restrict__ Wfc,
             const float* __restrict__ bfc, const float* __restrict__ cls,
             const float* __restrict__ pos, u16* __restrict__ h)
{
    int s = blockIdx.x;                // 0..1023 = n*16 + c
    int n = s >> 4, c = s & 15;
    int hc = threadIdx.x;
    float wr[INDIM];
    #pragma unroll
    for (int i=0;i<INDIM;i++) wr[i] = Wfc[hc*INDIM + i];
    float bb = bfc[hc];
    for (int l=0; l<TT; l++){
        const float* xr = x + (size_t)((n*TT + l)*CCH + c)*INDIM;
        float acc = bb;
        #pragma unroll
        for (int i=0;i<INDIM;i++) acc += xr[i]*wr[i];
        acc += pos[(size_t)(l*CCH + c)*HD + hc];
        h[((size_t)s*LSEQ + l)*HD + hc] = f2bf(acc);
    }
    #pragma unroll
    for (int l=TT; l<LSEQ; l++){
        float v = cls[(size_t)((l-TT)*CCH + c)*HD + hc]
                + pos[(size_t)(l*CCH + c)*HD + hc];
        h[((size_t)s*LSEQ + l)*HD + hc] = f2bf(v);
    }
}

// ---------------- graph constructor ----------------
__global__ __launch_bounds__(256)
void k_graph_m(const float* __restrict__ emb, const float* __restrict__ Wl,
               const float* __restrict__ bl, float* __restrict__ m)
{
    int r = blockIdx.x, o = threadIdx.x;
    __shared__ float e[HD];
    e[o] = emb[r*HD + o];
    __syncthreads();
    const float* w = Wl + (size_t)o*HD;
    float acc = bl[o];
    for (int k=0;k<HD;k++) acc += e[k]*w[k];
    m[r*HD + o] = tanhf(acc);
}

__global__ __launch_bounds__(256)
void k_graph_a(const float* __restrict__ m1, const float* __restrict__ m2,
               float* __restrict__ a)
{
    int t = threadIdx.x; int v = t >> 4, w = t & 15;
    __shared__ float adj[16][17];
    float s1=0.f, s2=0.f;
    for (int k=0;k<HD;k++){
        s1 += m1[v*HD+k]*m2[w*HD+k];
        s2 += m2[v*HD+k]*m1[w*HD+k];
    }
    float g = tanhf(s1 - s2); g = g > 0.f ? g : 0.f;
    adj[v][w] = g + (v==w ? 1.f : 0.f);
    __syncthreads();
    float rs = 0.f;
    #pragma unroll
    for (int j=0;j<16;j++) rs += adj[v][j];
    a[t] = adj[v][w] / rs;
}

// ---------------- MFMA GEMM, BK=64, counted-vmcnt 2-ahead pipeline (r9/r10 proven) ----
__global__ __launch_bounds__(256)
void k_gemmA(const u16* __restrict__ A, int lda,
             const u16* __restrict__ W, const float* __restrict__ bias,
             u16* __restrict__ C, int ldc, int K, int relu, int scat)
{
    __shared__ u16 smem[32768];            // 64 KB union
    u16* As0 = smem;                       // [2][4096]
    u16* As1 = smem + 8192;                // [2][4096]
    u16* Ws0 = smem + 16384;               // [2][4096]
    u16* Ws1 = smem + 24576;               // [2][4096]

    int t = threadIdx.x;
    int lane = t & 63, w = t >> 6;
    int wm = (w & 1)*64, wn = (w >> 1)*64;
    int fr = lane & 15, quad = lane >> 4;

    // XCD-aware tile remap (bijective; all grids here are %8==0)
    int nwg = gridDim.x * gridDim.y;
    int bid = blockIdx.y * gridDim.x + blockIdx.x;
    int tile = bid;
    if (!(nwg & 7)){
        int cpx = nwg >> 3;
        tile = (bid & 7)*cpx + (bid >> 3);
    }
    int bx = tile % gridDim.x, by = tile / gridDim.x;
    size_t mb = (size_t)by * 128;
    int nb = bx * 128;

    int srow = lane >> 2;
    int sslot = lane & 3;

    f32x4 acc[4][4] = {};

    auto STAGE = [&](int bb, int k0){     // 8 gloads per thread
        #pragma unroll
        for (int i=0;i<2;i++){
            int r = w*32 + i*16 + srow;
            int cw = sslot ^ ((r>>1)&3);
            gload_lds16(&A[(mb + r)*(size_t)lda + k0      + cw*8], &As0[bb*4096 + (w*32 + i*16)*32]);
            gload_lds16(&A[(mb + r)*(size_t)lda + k0 + 32 + cw*8], &As1[bb*4096 + (w*32 + i*16)*32]);
            gload_lds16(&W[(size_t)(nb + r)*K   + k0      + cw*8], &Ws0[bb*4096 + (w*32 + i*16)*32]);
            gload_lds16(&W[(size_t)(nb + r)*K   + k0 + 32 + cw*8], &Ws1[bb*4096 + (w*32 + i*16)*32]);
        }
    };
    auto COMPUTE = [&](int bb){
        short8 af0[4], af1[4], bf0[4], bf1[4];
        #pragma unroll
        for (int mt=0; mt<4; mt++){
            int r = wm + mt*16 + fr;
            int sw = (quad ^ ((r>>1)&3)) << 3;
            af0[mt] = *(const short8*)&As0[bb*4096 + r*32 + sw];
            af1[mt] = *(const short8*)&As1[bb*4096 + r*32 + sw];
        }
        #pragma unroll
        for (int nt=0; nt<4; nt++){
            int r = wn + nt*16 + fr;
            int sw = (quad ^ ((r>>1)&3)) << 3;
            bf0[nt] = *(const short8*)&Ws0[bb*4096 + r*32 + sw];
            bf1[nt] = *(const short8*)&Ws1[bb*4096 + r*32 + sw];
        }
        #pragma unroll
        for (int mt=0; mt<4; mt++)
            #pragma unroll
            for (int nt=0; nt<4; nt++){
                acc[mt][nt] = __builtin_amdgcn_mfma_f32_16x16x32_bf16(
                    af0[mt], bf0[nt], acc[mt][nt], 0, 0, 0);
                acc[mt][nt] = __builtin_amdgcn_mfma_f32_16x16x32_bf16(
                    af1[mt], bf1[nt], acc[mt][nt], 0, 0, 0);
            }
    };

    const int nst = K >> 6;
    STAGE(0, 0);
    if (nst > 1) STAGE(1, 64);
    int b = 0;
    for (int ts = 0; ts < nst; ++ts){
        if (ts + 1 < nst) asm volatile("s_waitcnt vmcnt(8)" ::: "memory");
        else              asm volatile("s_waitcnt vmcnt(0)" ::: "memory");
        __builtin_amdgcn_s_barrier();
        COMPUTE(b);
        __builtin_amdgcn_s_barrier();
        if (ts + 2 < nst) STAGE(b, (ts+2) << 6);
        b ^= 1;
    }

    // ---- epilogue: bias(+relu) -> LDS tile -> coalesced dwordx4 stores ----
    float bb4[4];
    #pragma unroll
    for (int nt=0; nt<4; nt++) bb4[nt] = bias[nb + wn + nt*16 + fr];
    u16* Ct = smem;                        // 128x128 u16
    #pragma unroll
    for (int mt=0; mt<4; mt++){
        int rw = wm + mt*16 + quad*4;
        #pragma unroll
        for (int nt=0; nt<4; nt++){
            int col = wn + nt*16 + fr;
            float v0 = acc[mt][nt][0] + bb4[nt];
            float v1 = acc[mt][nt][1] + bb4[nt];
            float v2 = acc[mt][nt][2] + bb4[nt];
            float v3 = acc[mt][nt][3] + bb4[nt];
            if (relu){
                v0 = v0 > 0.f ? v0 : 0.f;  v1 = v1 > 0.f ? v1 : 0.f;
                v2 = v2 > 0.f ? v2 : 0.f;  v3 = v3 > 0.f ? v3 : 0.f;
            }
            u32 p01 = cvtpk(v0, v1), p23 = cvtpk(v2, v3);
            Ct[(rw+0)*128 + col] = (u16)p01;
            Ct[(rw+1)*128 + col] = (u16)(p01 >> 16);
            Ct[(rw+2)*128 + col] = (u16)p23;
            Ct[(rw+3)*128 + col] = (u16)(p23 >> 16);
        }
    }
    __syncthreads();
    #pragma unroll
    for (int it=0; it<8; ++it){
        int row = it*16 + (t>>4);
        int seg = t & 15;
        size_t rg = mb + row;
        if (scat) rg = (rg >> 2)*LSEQ + TT + (rg & 3);
        *(short8*)&C[rg*(size_t)ldc + nb + seg*8] = *(const short8*)&Ct[row*128 + seg*8];
    }
}

// ------- MFMA GEMM (N=256) + bias + residual + LayerNorm fused, in-place h -------
// BK=64, counted-vmcnt 2-ahead (r9/r10 proven). LN epilogue via LDS cross-wave reduction.
__global__ __launch_bounds__(256)
void k_gemmC(const u16* __restrict__ A, int lda, int K,
             const u16* __restrict__ W, const float* __restrict__ bias,
             u16* __restrict__ h, const float* __restrict__ gam,
             const float* __restrict__ bet, size_t row0)
{
    __shared__ u16 smem[40960];            // 80 KB union
    u16* As0 = smem;                       // [2][2048]
    u16* As1 = smem + 4096;                // [2][2048]
    u16* Ws0 = smem + 8192;                // [2][8192]
    u16* Ws1 = smem + 24576;               // [2][8192]

    int t = threadIdx.x;
    int lane = t & 63, w = t >> 6;
    int fr = lane & 15, quad = lane >> 4;
    size_t mb = (size_t)blockIdx.x * 64;
    int srow = lane >> 2, sslot = lane & 3;

    f32x4 acc[4][4] = {};

    auto STAGE = [&](int bb, int k0){     // 10 gloads per thread
        {
            int r = w*16 + srow;
            int cw = sslot ^ ((r>>1)&3);
            gload_lds16(&A[(mb + r)*(size_t)lda + k0      + cw*8], &As0[bb*2048 + (w*16)*32]);
            gload_lds16(&A[(mb + r)*(size_t)lda + k0 + 32 + cw*8], &As1[bb*2048 + (w*16)*32]);
        }
        #pragma unroll
        for (int i=0;i<4;i++){
            int r = w*64 + i*16 + srow;
            int cw = sslot ^ ((r>>1)&3);
            gload_lds16(&W[(size_t)r*K + k0      + cw*8], &Ws0[bb*8192 + (w*64 + i*16)*32]);
            gload_lds16(&W[(size_t)r*K + k0 + 32 + cw*8], &Ws1[bb*8192 + (w*64 + i*16)*32]);
        }
    };
    auto COMPUTE = [&](int bb){
        short8 af0[4], af1[4], bf0[4], bf1[4];
        #pragma unroll
        for (int mt=0; mt<4; mt++){
            int ra = mt*16 + fr;
            int swa = (quad ^ ((ra>>1)&3)) << 3;
            af0[mt] = *(const short8*)&As0[bb*2048 + ra*32 + swa];
            af1[mt] = *(const short8*)&As1[bb*2048 + ra*32 + swa];
        }
        #pragma unroll
        for (int nt=0; nt<4; nt++){
            int rb = w*64 + nt*16 + fr;
            int swb = (quad ^ ((rb>>1)&3)) << 3;
            bf0[nt] = *(const short8*)&Ws0[bb*8192 + rb*32 + swb];
            bf1[nt] = *(const short8*)&Ws1[bb*8192 + rb*32 + swb];
        }
        #pragma unroll
        for (int mt=0; mt<4; mt++)
            #pragma unroll
            for (int nt=0; nt<4; nt++){
                acc[mt][nt] = __builtin_amdgcn_mfma_f32_16x16x32_bf16(
                    af0[mt], bf0[nt], acc[mt][nt], 0, 0, 0);
                acc[mt][nt] = __builtin_amdgcn_mfma_f32_16x16x32_bf16(
                    af1[mt], bf1[nt], acc[mt][nt], 0, 0, 0);
            }
    };

    const int nst = K >> 6;
    STAGE(0, 0);
    if (nst > 1) STAGE(1, 64);
    int b = 0;
    for (int ts = 0; ts < nst; ++ts){
        if (ts + 1 < nst) asm volatile("s_waitcnt vmcnt(10)" ::: "memory");
        else              asm volatile("s_waitcnt vmcnt(0)"  ::: "memory");
        __builtin_amdgcn_s_barrier();
        COMPUTE(b);
        __builtin_amdgcn_s_barrier();
        if (ts + 2 < nst) STAGE(b, (ts+2) << 6);
        b ^= 1;
    }

    // ---- epilogue: v = acc + bias + residual ----
    float bb4[4], gg[4], be[4];
    #pragma unroll
    for (int nt=0; nt<4; nt++){
        int col = w*64 + nt*16 + fr;
        bb4[nt] = bias[col]; gg[nt] = gam[col]; be[nt] = bet[col];
    }
    #pragma unroll
    for (int mt=0; mt<4; mt++){
        #pragma unroll
        for (int r=0; r<4; r++){
            size_t row = row0 + mb + mt*16 + quad*4 + r;
            #pragma unroll
            for (int nt=0; nt<4; nt++)
                acc[mt][nt][r] += bb4[nt] + bf2f(h[row*HD + w*64 + nt*16 + fr]);
        }
    }
    __syncthreads();
    float* red  = (float*)smem;            // 256 f32
    float* red2 = (float*)(smem + 512);    // 256 f32
    float ps[4][4];
    #pragma unroll
    for (int mt=0; mt<4; mt++)
        #pragma unroll
        for (int r=0; r<4; r++){
            float s = acc[mt][0][r] + acc[mt][1][r] + acc[mt][2][r] + acc[mt][3][r];
            s += __shfl_xor(s,1,64); s += __shfl_xor(s,2,64);
            s += __shfl_xor(s,4,64); s += __shfl_xor(s,8,64);
            ps[mt][r] = s;
        }
    if (fr == 0){
        #pragma unroll
        for (int mt=0; mt<4; mt++)
            #pragma unroll
            for (int r=0; r<4; r++)
                red[w*64 + mt*16 + quad*4 + r] = ps[mt][r];
    }
    __syncthreads();
    float mean[4][4];
    #pragma unroll
    for (int mt=0; mt<4; mt++)
        #pragma unroll
        for (int r=0; r<4; r++){
            int rl = mt*16 + quad*4 + r;
            mean[mt][r] = (red[rl] + red[64+rl] + red[128+rl] + red[192+rl]) * (1.f/256.f);
            float s = 0.f;
            #pragma unroll
            for (int nt=0; nt<4; nt++){ float d = acc[mt][nt][r] - mean[mt][r]; s += d*d; }
            s += __shfl_xor(s,1,64); s += __shfl_xor(s,2,64);
            s += __shfl_xor(s,4,64); s += __shfl_xor(s,8,64);
            ps[mt][r] = s;
        }
    if (fr == 0){
        #pragma unroll
        for (int mt=0; mt<4; mt++)
            #pragma unroll
            for (int r=0; r<4; r++)
                red2[w*64 + mt*16 + quad*4 + r] = ps[mt][r];
    }
    __syncthreads();
    // ---- normalize -> LDS tile -> coalesced stores ----
    u16* Ct = smem + 8192;                 // 64x256 u16
    #pragma unroll
    for (int mt=0; mt<4; mt++)
        #pragma unroll
        for (int r=0; r<4; r++){
            int rl = mt*16 + quad*4 + r;
            float inv = rsqrtf((red2[rl] + red2[64+rl] + red2[128+rl] + red2[192+rl])
                               * (1.f/256.f) + EPSV);
            float o0 = (acc[mt][0][r] - mean[mt][r]) * inv * gg[0] + be[0];
            float o1 = (acc[mt][1][r] - mean[mt][r]) * inv * gg[1] + be[1];
            float o2 = (acc[mt][2][r] - mean[mt][r]) * inv * gg[2] + be[2];
            float o3 = (acc[mt][3][r] - mean[mt][r]) * inv * gg[3] + be[3];
            u32 p01 = cvtpk(o0, o1), p23 = cvtpk(o2, o3);
            Ct[rl*256 + w*64 +  0 + fr] = (u16)p01;
            Ct[rl*256 + w*64 + 16 + fr] = (u16)(p01 >> 16);
            Ct[rl*256 + w*64 + 32 + fr] = (u16)p23;
            Ct[rl*256 + w*64 + 48 + fr] = (u16)(p23 >> 16);
        }
    __syncthreads();
    #pragma unroll
    for (int it=0; it<8; ++it){
        int row = it*8 + (t>>5);
        int seg = t & 31;
        *(short8*)&h[(row0 + mb + row)*HD + seg*8] = *(const short8*)&Ct[row*256 + seg*8];
    }
}

// ---------------- MFMA attention, 8-wave occupancy variant (r10) + T5 setprio ----------------
#define KS_STR 40
#define VT_STR 136
__global__ __launch_bounds__(512)
void k_attn(u16* __restrict__ qkv)
{
    __shared__ u16 smem[24576];   // 48 KB. stage: Ks 2x4480 @0 | Vt 2x4352 @8960 (dead after prefetch)
                                  // strips: Ph [0,12288) | Pv [12288,24576), per (head,wsgrp) offsets
    int t = threadIdx.x;
    int w = t >> 6, lane = t & 63;
    int fr = lane & 15, quad = lane >> 4;
    int p = t >> 8, t2 = t & 255;          // staging half (one per head)
    u16* Ks = smem + p*4480;
    u16* Vt = smem + 8960 + p*4352;

    {
        int gp = blockIdx.x*2 + p;
        size_t base = (size_t)(gp >> 3)*LSEQ*768 + (gp & 7)*32;
        for (int idx = t2; idx < 1792; idx += 256){
            int key = idx >> 4, d2 = (idx & 15) << 1;
            u32 kv = (key < LSEQ) ? *(const u32*)&qkv[base + (size_t)key*768 + 256 + d2] : 0u;
            *(u32*)&Ks[key*KS_STR + d2] = kv;
        }
        // key-major V transpose staging: lanes stride-1 in key -> conflict-free writes
        for (int idx = t2; idx < 2048; idx += 256){
            int key = idx & 127, d2 = (idx >> 7) << 1;
            u32 vv = (key < LSEQ) ? *(const u32*)&qkv[base + (size_t)key*768 + 512 + d2] : 0u;
            Vt[ d2   *VT_STR + key] = (u16)(vv & 0xffffu);
            Vt[(d2+1)*VT_STR + key] = (u16)(vv >> 16);
        }
    }
    __syncthreads();

    int hp = w >> 2;              // head within block (0,1)
    int ws = w & 3;               // strip group (0..3)
    int gp = blockIdx.x*2 + hp;
    size_t base = (size_t)(gp >> 3)*LSEQ*768 + (gp & 7)*32;
    u16* Ksw = smem + hp*4480;
    u16* Vtw = smem + 8960 + hp*4352;

    short8 kf[7];
    #pragma unroll
    for (int nt=0; nt<7; nt++)
        kf[nt] = *(const short8*)&Ksw[(nt*16 + fr)*KS_STR + quad*8];
    short8 vfr[4][2];
    #pragma unroll
    for (int ks=0; ks<4; ks++)
        #pragma unroll
        for (int nt=0; nt<2; nt++)
            vfr[ks][nt] = *(const short8*)&Vtw[(nt*16 + fr)*VT_STR + ks*32 + quad*8];

    // strip groups: {6}, {0,5}, {1,4}, {2,3} — 7 S-units each
    int smask = (ws==0) ? 0x40 : (ws==1) ? 0x21 : (ws==2) ? 0x12 : 0x0C;
    // prefetch q fragments for this wave's strips (before any output store can alias)
    short8 qfs[7];
    #pragma unroll
    for (int st=0; st<7; ++st){
        if (!((smask >> st) & 1)) continue;
        int q = st*16 + fr;
        short8 z = {};
        qfs[st] = (q < LSEQ) ? *(const short8*)&qkv[base + (size_t)q*768 + quad*8] : z;
    }
    __syncthreads();   // all waves done reading Ks/Vt before Ph/Pv overlay reuse

    // per-(head, strip-group) P buffers: sizes 2048/1536/1536/1024 u16
    int pref = ws ? (1536*ws + 512) : 0;
    u16* Ph = smem + hp*6144 + pref;            // [0, 12288)
    u16* Pv = smem + 12288 + hp*6144 + pref;    // [12288, 24576)

    const float cs = 0.17677669529663687f * 1.4426950408889634f;  // (1/sqrt32)*log2(e)
    #pragma unroll
    for (int st = 0; st < 7; ++st){
        if (!((smask >> st) & 1)) continue;
        const int ntile = (st == 6) ? 7 : (st + 1);
        const int nks   = (st == 6) ? 4 : (st/2 + 1);
        f32x4 S[7];
        __builtin_amdgcn_s_setprio(1);          // T5: favor this wave's QK^T MFMA cluster
        #pragma unroll
        for (int nt=0; nt<7; nt++){
            if (nt >= ntile) continue;
            f32x4 z = {};
            S[nt] = __builtin_amdgcn_mfma_f32_16x16x32_bf16(qfs[st], kf[nt], z, 0,0,0);
        }
        __builtin_amdgcn_s_setprio(0);
        // scale (in log2 domain); mask ONLY the last tile (full tiles causal-valid)
        float mx[4] = {-1e30f,-1e30f,-1e30f,-1e30f};
        #pragma unroll
        for (int nt=0;nt<7;nt++){
            if (nt >= ntile) continue;
            #pragma unroll
            for (int r=0;r<4;r++){
                float s = S[nt][r]*cs;
                if (nt == ntile-1){
                    int qr = st*16 + quad*4 + r;
                    int jmax = (qr < TT) ? qr : (LSEQ-1);
                    s = ((nt*16 + fr) <= jmax) ? s : -1e30f;
                }
                S[nt][r] = s;
                mx[r] = fmaxf(mx[r], s);
            }
        }
        #pragma unroll
        for (int r=0;r<4;r++){
            #pragma unroll
            for (int m=1;m<16;m<<=1) mx[r] = fmaxf(mx[r], __shfl_xor(mx[r], m, 64));
        }
        float l4[4] = {0.f,0.f,0.f,0.f};
        #pragma unroll
        for (int r=0;r<4;r++){
            #pragma unroll
            for (int nt=0;nt<7;nt++){
                if (nt >= ntile) continue;
                float pv = EXP2F(S[nt][r] - mx[r]);
                S[nt][r] = pv;
                l4[r] += pv;
            }
        }
        #pragma unroll
        for (int r=0;r<4;r++){
            #pragma unroll
            for (int m=1;m<16;m<<=1) l4[r] += __shfl_xor(l4[r], m, 64);
        }
        // WAR fence: this wave's previous strip's Ph/Pv reads must complete (buffers private)
        asm volatile("s_waitcnt lgkmcnt(0)" ::: "memory");
        // write P_hi + P_lo via packed cvt; panel layout [ks][16 rows][32 k], XOR swizzle
        #pragma unroll
        for (int nt=0;nt<7;nt++){
            if (nt >= ntile) continue;
            u32 h01 = cvtpk(S[nt][0], S[nt][1]);
            u32 h23 = cvtpk(S[nt][2], S[nt][3]);
            float l0 = S[nt][0] - lo16(h01);
            float l1 = S[nt][1] - hi16(h01);
            float l2 = S[nt][2] - lo16(h23);
            float l3 = S[nt][3] - hi16(h23);
            u32 g01 = cvtpk(l0, l1);
            u32 g23 = cvtpk(l2, l3);
            u16 hv[4] = {(u16)h01, (u16)(h01>>16), (u16)h23, (u16)(h23>>16)};
            u16 lv[4] = {(u16)g01, (u16)(g01>>16), (u16)g23, (u16)(g23>>16)};
            #pragma unroll
            for (int r=0;r<4;r++){
                int row = quad*4 + r;
                int a = (nt>>1)*512 + row*32 + ((((nt&1)<<4) + fr) ^ (((row>>1)&3)<<3));
                Ph[a] = hv[r];
                Pv[a] = lv[r];
            }
        }
        if (ntile*16 < nks*32){
            #pragma unroll
            for (int r=0;r<4;r++){
                int row = quad*4 + r;
                int a = (ntile>>1)*512 + row*32 + ((((ntile&1)<<4) + fr) ^ (((row>>1)&3)<<3));
                Ph[a] = 0;
                Pv[a] = 0;
            }
        }
        asm volatile("s_waitcnt lgkmcnt(0)" ::: "memory");
        f32x4 D[2] = {};
        __builtin_amdgcn_s_setprio(1);          // T5: favor PV MFMA cluster
        #pragma unroll
        for (int ks=0; ks<4; ks++){
            if (ks >= nks) continue;
            int a = ks*512 + fr*32 + ((quad ^ ((fr>>1)&3)) << 3);
            short8 ph = *(const short8*)&Ph[a];
            short8 pl = *(const short8*)&Pv[a];
            #pragma unroll
            for (int nt=0; nt<2; nt++){
                D[nt] = __builtin_amdgcn_mfma_f32_16x16x32_bf16(ph, vfr[ks][nt], D[nt], 0,0,0);
                D[nt] = __builtin_amdgcn_mfma_f32_16x16x32_bf16(pl, vfr[ks][nt], D[nt], 0,0,0);
            }
        }
        __builtin_amdgcn_s_setprio(0);
        #pragma unroll
        for (int r=0;r<4;r++){
            int qr = st*16 + quad*4 + r;
            if (qr < LSEQ){
                float inv = 1.f / l4[r];
                u32 o = cvtpk(D[0][r]*inv, D[1][r]*inv);
                qkv[base + (size_t)qr*768 +      fr] = (u16)o;
                qkv[base + (size_t)qr*768 + 16 + fr] = (u16)(o >> 16);
            }
        }
        // no trailing drain: next strip's WAR fence orders LDS; global rows disjoint
    }
}

// ---------------- mixprop prep ----------------
__global__ __launch_bounds__(256)
void k_mixprep(const u16* __restrict__ h, const float* __restrict__ a,
               u16* __restrict__ amid)
{
    int n = blockIdx.x >> 2, tt = blockIdx.x & 3;
    __shared__ float xs[256][17], h1s[256][17], h2s[256][17];
    __shared__ float as[16][17];
    int t = threadIdx.x;
    as[t>>4][t&15] = a[t];
    for (int idx=t; idx<4096; idx+=256){
        int w = idx >> 8, hc = idx & 255;
        xs[hc][w] = bf2f(h[((size_t)(n*16 + w)*LSEQ + TT + tt)*HD + hc]);
    }
    __syncthreads();
    for (int idx=t; idx<4096; idx+=256){
        int v = idx & 15, hc = idx >> 4;
        float acc = 0.f;
        #pragma unroll
        for (int w=0;w<16;w++) acc += as[v][w]*xs[hc][w];
        h1s[hc][v] = acc;
    }
    __syncthreads();
    for (int idx=t; idx<4096; idx+=256){
        int v = idx & 15, hc = idx >> 4;
        float acc = 0.f;
        #pragma unroll
        for (int w=0;w<16;w++) acc += as[v][w]*h1s[hc][w];
        h2s[hc][v] = acc;
    }
    __syncthreads();
    int hc = t;
    #pragma unroll
    for (int w=0;w<16;w++){
        size_t row = (size_t)((n*16 + w)*4 + tt);
        amid[row*768 +       hc] = f2bf(xs[hc][w]);
        amid[row*768 + 256 + hc] = f2bf(h1s[hc][w]);
        amid[row*768 + 512 + hc] = f2bf(h2s[hc][w]);
    }
}

// ---------------- head ----------------
__global__ __launch_bounds__(256)
void k_z(const u16* __restrict__ h, u16* __restrict__ z)
{
    int bid = blockIdx.x, t = threadIdx.x;     // bid = n*16+c
    #pragma unroll
    for (int tc=0;tc<4;tc++)
        z[((size_t)bid*4 + tc)*HD + t] = f2bf(tanhf(bf2f(h[((size_t)bid*LSEQ + TT + tc)*HD + t])));
}

__global__ __launch_bounds__(256)
void k_head1p(const u16* __restrict__ z, const float* __restrict__ Wd1,
              float* __restrict__ d1p)
{
    __shared__ float zch[64][137];
    __shared__ float wt[16][137];
    int t = threadIdx.x;
    int col = t & 15, rgrp = t >> 4;
    int ob = blockIdx.x * 16;
    int kb = blockIdx.y;
    float acc[4] = {0.f,0.f,0.f,0.f};
    for (int kc=0; kc<1024; kc+=128){
        int base_k = kb*1024 + kc;
        #pragma unroll
        for (int jj=0; jj<16; jj++){
            int idx = t + jj*256;
            int n = idx >> 6, k2 = (idx & 63) << 1;
            u32 r = *(const u32*)&z[(size_t)n*16384 + base_k + k2];
            zch[n][k2] = lo16(r); zch[n][k2+1] = hi16(r);
        }
        #pragma unroll
        for (int jj=0; jj<2; jj++){
            int idx = t + jj*256;
            int r = idx >> 5, k4 = (idx & 31) << 2;
            float4 w4 = *(const float4*)&Wd1[(size_t)(ob + r)*16384 + base_k + k4];
            wt[r][k4] = w4.x; wt[r][k4+1] = w4.y; wt[r][k4+2] = w4.z; wt[r][k4+3] = w4.w;
        }
        __syncthreads();
        for (int k=0;k<128;k++){
            float wv = wt[col][k];
            #pragma unroll
            for (int u=0;u<4;u++) acc[u] += zch[rgrp + 16*u][k]*wv;
        }
        __syncthreads();
    }
    #pragma unroll
    for (int u=0;u<4;u++)
        d1p[(size_t)(kb*64 + rgrp + 16*u)*HD + ob + col] = acc[u];
}

__global__ __launch_bounds__(256)
void k_headf(const float* __restrict__ d1p, const float* __restrict__ bd1,
             const float* __restrict__ Wd2, const float* __restrict__ bd2,
             float* __restrict__ out)
{
    __shared__ float red[4];
    int n = blockIdx.x, c = threadIdx.x;
    float s = 0.f;
    #pragma unroll
    for (int kb=0; kb<16; kb++) s += d1p[(size_t)(kb*64 + n)*HD + c];
    float xx = s + bd1[c];
    float ge = 0.5f*xx*(1.f + erff(xx*0.70710678118654752f));
    float p = ge * Wd2[c];
    #pragma unroll
    for (int m=1;m<64;m<<=1) p += __shfl_xor(p, m, 64);
    if ((c & 63) == 0) red[c >> 6] = p;
    __syncthreads();
    if (c == 0) out[n] = red[0]+red[1]+red[2]+red[3] + bd2[0];
}

// ---------------- launch ----------------
extern "C" void kernel_launch(void* const* d_in, const int* in_sizes, int n_in,
                              void* d_out, int out_size, void* d_ws, size_t ws_size,
                              hipStream_t stream)
{
    const float* x    = (const float*)d_in[0];
    const float* Wfc  = (const float*)d_in[3];
    const float* bfc  = (const float*)d_in[4];
    const float* cls  = (const float*)d_in[5];
    const float* pos  = (const float*)d_in[6];
    const float* emb1 = (const float*)d_in[7];
    const float* emb2 = (const float*)d_in[8];
    const float* Wl1  = (const float*)d_in[9];
    const float* bl1  = (const float*)d_in[10];
    const float* Wl2  = (const float*)d_in[11];
    const float* bl2  = (const float*)d_in[12];
    const float* Wqkv = (const float*)d_in[13];
    const float* bqkv = (const float*)d_in[14];
    const float* Wo   = (const float*)d_in[15];
    const float* bo   = (const float*)d_in[16];
    const float* W1   = (const float*)d_in[17];
    const float* b1   = (const float*)d_in[18];
    const float* W2   = (const float*)d_in[19];
    const float* b2   = (const float*)d_in[20];
    const float* ln1g = (const float*)d_in[21];
    const float* ln1b = (const float*)d_in[22];
    const float* ln2g = (const float*)d_in[23];
    const float* ln2b = (const float*)d_in[24];
    const float* Wmlp = (const float*)d_in[25];
    const float* bmlp = (const float*)d_in[26];
    const float* Wd1  = (const float*)d_in[27];
    const float* bd1  = (const float*)d_in[28];
    const float* Wd2  = (const float*)d_in[29];
    const float* bd2  = (const float*)d_in[30];

    // dynamic chunk selection (2048 B/token)
    int NCH = 8;
    {
        const size_t fixed = 63145088 + (1<<20);
        if      (fixed + (size_t)MTOK    *2048 <= ws_size) NCH = 1;
        else if (fixed + (size_t)(MTOK/2)*2048 <= ws_size) NCH = 2;
        else if (fixed + (size_t)(MTOK/4)*2048 <= ws_size) NCH = 4;
    }
    const int RCH = MTOK / NCH;
    const int SCH = BSEQ / NCH;

    // workspace layout
    u16* h    = (u16*)d_ws;                    // 26,214,400 u16
    u16* buf  = h    + (size_t)MTOK*HD;        // RCH*1024  (qkv / ff1 / mixprop amid)
    u16* wq   = buf  + (size_t)RCH*1024;       //    786,432
    u16* wo   = wq   + (size_t)4*768*256;      //    262,144
    u16* w1   = wo   + (size_t)4*256*256;      //  1,048,576
    u16* w2   = w1   + (size_t)4*1024*256;     //  1,048,576
    u16* wmb  = w2   + (size_t)4*256*1024;     //    589,824
    u16* zb   = wmb  + (size_t)3*256*768;      //  1,048,576
    float* fp = (float*)(zb + (size_t)BSZ*16384);
    float* m1  = fp;
    float* m2  = m1 + CCH*HD;
    float* an  = m2 + CCH*HD;
    float* d1p = an + CCH*CCH;                 // 16*64*256

    // one-time weight prep
    k_cvt<<<512, 256, 0, stream>>>(Wqkv, wq, 4*768*256);
    k_cvt<<<256, 256, 0, stream>>>(Wo,   wo, 4*256*256);
    k_cvt<<<512, 256, 0, stream>>>(W1,   w1, 4*1024*256);
    k_cvt<<<512, 256, 0, stream>>>(W2,   w2, 4*256*1024);
    k_cvt<<<256, 256, 0, stream>>>(Wmlp, wmb, 3*256*768);

    k_embed<<<BSEQ, 256, 0, stream>>>(x, Wfc, bfc, cls, pos, h);
    k_graph_m<<<16, 256, 0, stream>>>(emb1, Wl1, bl1, m1);
    k_graph_m<<<16, 256, 0, stream>>>(emb2, Wl2, bl2, m2);
    k_graph_a<<<1, 256, 0, stream>>>(m1, m2, an);

    for (int l=0; l<NLAY; l++){
        if (l > 0){
            k_mixprep<<<BSZ*NCLS, 256, 0, stream>>>(h, an, buf);
            k_gemmA<<<dim3(256/128, 4096/128), 256, 0, stream>>>(
                buf, 768, wmb + (size_t)(l-1)*256*768, bmlp + (size_t)(l-1)*HD,
                h, HD, 768, 0, 1);
        }

        for (int c=0; c<NCH; c++){
            size_t row0 = (size_t)c * RCH;
            k_gemmA<<<dim3(768/128, RCH/128), 256, 0, stream>>>(
                h + row0*HD, HD, wq + (size_t)l*768*256, bqkv + (size_t)l*768,
                buf, 768, HD, 0, 0);
            k_attn<<<SCH*NHEAD/2, 512, 0, stream>>>(buf);
            // out-proj + residual + LN1 fused (reads q-slot of buf, lda=768)
            k_gemmC<<<RCH/64, 256, 0, stream>>>(
                buf, 768, HD, wo + (size_t)l*256*256, bo + (size_t)l*HD,
                h, ln1g + (size_t)l*HD, ln1b + (size_t)l*HD, row0);
            k_gemmA<<<dim3(1024/128, RCH/128), 256, 0, stream>>>(
                h + row0*HD, HD, w1 + (size_t)l*1024*256, b1 + (size_t)l*1024,
                buf, 1024, HD, 1, 0);
            // FF2 + residual + LN2 fused
            k_gemmC<<<RCH/64, 256, 0, stream>>>(
                buf, 1024, 1024, w2 + (size_t)l*256*1024, b2 + (size_t)l*HD,
                h, ln2g + (size_t)l*HD, ln2b + (size_t)l*HD, row0);
        }
    }

    k_z<<<BSZ*CCH, 256, 0, stream>>>(h, zb);
    k_head1p<<<dim3(16, 16), 256, 0, stream>>>(zb, Wd1, d1p);
    k_headf<<<BSZ, 256, 0, stream>>>(d1p, bd1, Wd2, bd2, (float*)d_out);
}

// Round 14
// 1927.074 us; speedup vs baseline: 2.1194x; 1.0086x over previous
//
#include <hip/hip_runtime.h>
#include <hip/hip_bf16.h>
#include <math.h>

typedef unsigned short u16;
typedef unsigned int   u32;
typedef __attribute__((ext_vector_type(8))) short short8;   // 8 bf16 = 4 VGPRs
typedef __attribute__((ext_vector_type(4))) float f32x4;

// ---- model dims ----
#define BSZ   64
#define TT    96
#define CCH   16
#define INDIM 16
#define HD    256
#define NHEAD 8
#define DHEAD 32
#define NCLS  4
#define LSEQ  100      // TT + NCLS
#define NLAY  4
#define EPSV  1e-5f
#define BSEQ  (BSZ*CCH)        // 1024 sequences
#define MTOK  (BSEQ*LSEQ)      // 102400 tokens

#if __has_builtin(__builtin_amdgcn_exp2f)
#define EXP2F __builtin_amdgcn_exp2f
#else
#define EXP2F exp2f
#endif

__device__ __forceinline__ float bf2f(u16 x){ return __uint_as_float(((u32)x)<<16); }
__device__ __forceinline__ u16 f2bf(float f){
    u32 u = __float_as_uint(f);
    u32 r = (u + 0x7fffu + ((u>>16)&1u)) >> 16;
    return (u16)r;
}
__device__ __forceinline__ float lo16(u32 r){ return __uint_as_float(r<<16); }
__device__ __forceinline__ float hi16(u32 r){ return __uint_as_float(r&0xffff0000u); }

// HW packed f32->bf16 (RNE), 1 instr per 2 elements
__device__ __forceinline__ u32 cvtpk(float lo, float hi){
    u32 r;
    asm("v_cvt_pk_bf16_f32 %0, %1, %2" : "=v"(r) : "v"(lo), "v"(hi));
    return r;
}

// async global->LDS, 16B per lane; LDS dest = (wave-uniform base) + lane*16
__device__ __forceinline__ void gload_lds16(const u16* g, u16* l){
    __builtin_amdgcn_global_load_lds(
        (const __attribute__((address_space(1))) unsigned int*)g,
        (__attribute__((address_space(3))) unsigned int*)l, 16, 0, 0);
}

// ---------------- f32 -> bf16 bulk convert ----------------
__global__ __launch_bounds__(256)
void k_cvt(const float* __restrict__ src, u16* __restrict__ dst, int n)
{
    for (int i = blockIdx.x*256 + threadIdx.x; i < n; i += gridDim.x*256)
        dst[i] = f2bf(src[i]);
}

// ---------------- embed (x row loads vectorized as 4x float4; math order identical) ----
__global__ __launch_bounds__(256)
void k_embed(const float* __restrict__ x, const float* __restrict__ Wfc,
             const float* __restrict__ bfc, const float* __restrict__ cls,
             const float* __restrict__ pos, u16* __restrict__ h)
{
    int s = blockIdx.x;                // 0..1023 = n*16 + c
    int n = s >> 4, c = s & 15;
    int hc = threadIdx.x;
    float wr[INDIM];
    #pragma unroll
    for (int i=0;i<INDIM;i++) wr[i] = Wfc[hc*INDIM + i];
    float bb = bfc[hc];
    for (int l=0; l<TT; l++){
        const float* xr = x + (size_t)((n*TT + l)*CCH + c)*INDIM;
        float xv[INDIM];
        #pragma unroll
        for (int i=0;i<4;i++){
            float4 v4 = *(const float4*)&xr[i*4];
            xv[i*4+0]=v4.x; xv[i*4+1]=v4.y; xv[i*4+2]=v4.z; xv[i*4+3]=v4.w;
        }
        float acc = bb;
        #pragma unroll
        for (int i=0;i<INDIM;i++) acc += xv[i]*wr[i];
        acc += pos[(size_t)(l*CCH + c)*HD + hc];
        h[((size_t)s*LSEQ + l)*HD + hc] = f2bf(acc);
    }
    #pragma unroll
    for (int l=TT; l<LSEQ; l++){
        float v = cls[(size_t)((l-TT)*CCH + c)*HD + hc]
                + pos[(size_t)(l*CCH + c)*HD + hc];
        h[((size_t)s*LSEQ + l)*HD + hc] = f2bf(v);
    }
}

// ---------------- graph constructor ----------------
__global__ __launch_bounds__(256)
void k_graph_m(const float* __restrict__ emb, const float* __restrict__ Wl,
               const float* __restrict__ bl, float* __restrict__ m)
{
    int r = blockIdx.x, o = threadIdx.x;
    __shared__ float e[HD];
    e[o] = emb[r*HD + o];
    __syncthreads();
    const float* w = Wl + (size_t)o*HD;
    float acc = bl[o];
    for (int k=0;k<HD;k++) acc += e[k]*w[k];
    m[r*HD + o] = tanhf(acc);
}

__global__ __launch_bounds__(256)
void k_graph_a(const float* __restrict__ m1, const float* __restrict__ m2,
               float* __restrict__ a)
{
    int t = threadIdx.x; int v = t >> 4, w = t & 15;
    __shared__ float adj[16][17];
    float s1=0.f, s2=0.f;
    for (int k=0;k<HD;k++){
        s1 += m1[v*HD+k]*m2[w*HD+k];
        s2 += m2[v*HD+k]*m1[w*HD+k];
    }
    float g = tanhf(s1 - s2); g = g > 0.f ? g : 0.f;
    adj[v][w] = g + (v==w ? 1.f : 0.f);
    __syncthreads();
    float rs = 0.f;
    #pragma unroll
    for (int j=0;j<16;j++) rs += adj[v][j];
    a[t] = adj[v][w] / rs;
}

// ---------------- MFMA GEMM, BK=64, counted-vmcnt 2-ahead pipeline (r12 proven) ----
__global__ __launch_bounds__(256)
void k_gemmA(const u16* __restrict__ A, int lda,
             const u16* __restrict__ W, const float* __restrict__ bias,
             u16* __restrict__ C, int ldc, int K, int relu, int scat)
{
    __shared__ u16 smem[32768];            // 64 KB union
    u16* As0 = smem;                       // [2][4096]
    u16* As1 = smem + 8192;                // [2][4096]
    u16* Ws0 = smem + 16384;               // [2][4096]
    u16* Ws1 = smem + 24576;               // [2][4096]

    int t = threadIdx.x;
    int lane = t & 63, w = t >> 6;
    int wm = (w & 1)*64, wn = (w >> 1)*64;
    int fr = lane & 15, quad = lane >> 4;

    // XCD-aware tile remap (bijective; all grids here are %8==0)
    int nwg = gridDim.x * gridDim.y;
    int bid = blockIdx.y * gridDim.x + blockIdx.x;
    int tile = bid;
    if (!(nwg & 7)){
        int cpx = nwg >> 3;
        tile = (bid & 7)*cpx + (bid >> 3);
    }
    int bx = tile % gridDim.x, by = tile / gridDim.x;
    size_t mb = (size_t)by * 128;
    int nb = bx * 128;

    int srow = lane >> 2;
    int sslot = lane & 3;

    f32x4 acc[4][4] = {};

    auto STAGE = [&](int bb, int k0){     // 8 gloads per thread
        #pragma unroll
        for (int i=0;i<2;i++){
            int r = w*32 + i*16 + srow;
            int cw = sslot ^ ((r>>1)&3);
            gload_lds16(&A[(mb + r)*(size_t)lda + k0      + cw*8], &As0[bb*4096 + (w*32 + i*16)*32]);
            gload_lds16(&A[(mb + r)*(size_t)lda + k0 + 32 + cw*8], &As1[bb*4096 + (w*32 + i*16)*32]);
            gload_lds16(&W[(size_t)(nb + r)*K   + k0      + cw*8], &Ws0[bb*4096 + (w*32 + i*16)*32]);
            gload_lds16(&W[(size_t)(nb + r)*K   + k0 + 32 + cw*8], &Ws1[bb*4096 + (w*32 + i*16)*32]);
        }
    };
    auto COMPUTE = [&](int bb){
        short8 af0[4], af1[4], bf0[4], bf1[4];
        #pragma unroll
        for (int mt=0; mt<4; mt++){
            int r = wm + mt*16 + fr;
            int sw = (quad ^ ((r>>1)&3)) << 3;
            af0[mt] = *(const short8*)&As0[bb*4096 + r*32 + sw];
            af1[mt] = *(const short8*)&As1[bb*4096 + r*32 + sw];
        }
        #pragma unroll
        for (int nt=0; nt<4; nt++){
            int r = wn + nt*16 + fr;
            int sw = (quad ^ ((r>>1)&3)) << 3;
            bf0[nt] = *(const short8*)&Ws0[bb*4096 + r*32 + sw];
            bf1[nt] = *(const short8*)&Ws1[bb*4096 + r*32 + sw];
        }
        #pragma unroll
        for (int mt=0; mt<4; mt++)
            #pragma unroll
            for (int nt=0; nt<4; nt++){
                acc[mt][nt] = __builtin_amdgcn_mfma_f32_16x16x32_bf16(
                    af0[mt], bf0[nt], acc[mt][nt], 0, 0, 0);
                acc[mt][nt] = __builtin_amdgcn_mfma_f32_16x16x32_bf16(
                    af1[mt], bf1[nt], acc[mt][nt], 0, 0, 0);
            }
    };

    const int nst = K >> 6;
    STAGE(0, 0);
    if (nst > 1) STAGE(1, 64);
    int b = 0;
    for (int ts = 0; ts < nst; ++ts){
        if (ts + 1 < nst) asm volatile("s_waitcnt vmcnt(8)" ::: "memory");
        else              asm volatile("s_waitcnt vmcnt(0)" ::: "memory");
        __builtin_amdgcn_s_barrier();
        COMPUTE(b);
        __builtin_amdgcn_s_barrier();
        if (ts + 2 < nst) STAGE(b, (ts+2) << 6);
        b ^= 1;
    }

    // ---- epilogue: bias(+relu) -> LDS tile -> coalesced dwordx4 stores ----
    float bb4[4];
    #pragma unroll
    for (int nt=0; nt<4; nt++) bb4[nt] = bias[nb + wn + nt*16 + fr];
    u16* Ct = smem;                        // 128x128 u16
    #pragma unroll
    for (int mt=0; mt<4; mt++){
        int rw = wm + mt*16 + quad*4;
        #pragma unroll
        for (int nt=0; nt<4; nt++){
            int col = wn + nt*16 + fr;
            float v0 = acc[mt][nt][0] + bb4[nt];
            float v1 = acc[mt][nt][1] + bb4[nt];
            float v2 = acc[mt][nt][2] + bb4[nt];
            float v3 = acc[mt][nt][3] + bb4[nt];
            if (relu){
                v0 = v0 > 0.f ? v0 : 0.f;  v1 = v1 > 0.f ? v1 : 0.f;
                v2 = v2 > 0.f ? v2 : 0.f;  v3 = v3 > 0.f ? v3 : 0.f;
            }
            u32 p01 = cvtpk(v0, v1), p23 = cvtpk(v2, v3);
            Ct[(rw+0)*128 + col] = (u16)p01;
            Ct[(rw+1)*128 + col] = (u16)(p01 >> 16);
            Ct[(rw+2)*128 + col] = (u16)p23;
            Ct[(rw+3)*128 + col] = (u16)(p23 >> 16);
        }
    }
    __syncthreads();
    #pragma unroll
    for (int it=0; it<8; ++it){
        int row = it*16 + (t>>4);
        int seg = t & 15;
        size_t rg = mb + row;
        if (scat) rg = (rg >> 2)*LSEQ + TT + (rg & 3);
        *(short8*)&C[rg*(size_t)ldc + nb + seg*8] = *(const short8*)&Ct[row*128 + seg*8];
    }
}

// ------- MFMA GEMM (N=256) + bias + residual + LayerNorm fused, in-place h -------
// BK=64, counted-vmcnt 2-ahead (r12 proven). LN epilogue via LDS cross-wave reduction.
__global__ __launch_bounds__(256)
void k_gemmC(const u16* __restrict__ A, int lda, int K,
             const u16* __restrict__ W, const float* __restrict__ bias,
             u16* __restrict__ h, const float* __restrict__ gam,
             const float* __restrict__ bet, size_t row0)
{
    __shared__ u16 smem[40960];            // 80 KB union
    u16* As0 = smem;                       // [2][2048]
    u16* As1 = smem + 4096;                // [2][2048]
    u16* Ws0 = smem + 8192;                // [2][8192]
    u16* Ws1 = smem + 24576;               // [2][8192]

    int t = threadIdx.x;
    int lane = t & 63, w = t >> 6;
    int fr = lane & 15, quad = lane >> 4;
    size_t mb = (size_t)blockIdx.x * 64;
    int srow = lane >> 2, sslot = lane & 3;

    f32x4 acc[4][4] = {};

    auto STAGE = [&](int bb, int k0){     // 10 gloads per thread
        {
            int r = w*16 + srow;
            int cw = sslot ^ ((r>>1)&3);
            gload_lds16(&A[(mb + r)*(size_t)lda + k0      + cw*8], &As0[bb*2048 + (w*16)*32]);
            gload_lds16(&A[(mb + r)*(size_t)lda + k0 + 32 + cw*8], &As1[bb*2048 + (w*16)*32]);
        }
        #pragma unroll
        for (int i=0;i<4;i++){
            int r = w*64 + i*16 + srow;
            int cw = sslot ^ ((r>>1)&3);
            gload_lds16(&W[(size_t)r*K + k0      + cw*8], &Ws0[bb*8192 + (w*64 + i*16)*32]);
            gload_lds16(&W[(size_t)r*K + k0 + 32 + cw*8], &Ws1[bb*8192 + (w*64 + i*16)*32]);
        }
    };
    auto COMPUTE = [&](int bb){
        short8 af0[4], af1[4], bf0[4], bf1[4];
        #pragma unroll
        for (int mt=0; mt<4; mt++){
            int ra = mt*16 + fr;
            int swa = (quad ^ ((ra>>1)&3)) << 3;
            af0[mt] = *(const short8*)&As0[bb*2048 + ra*32 + swa];
            af1[mt] = *(const short8*)&As1[bb*2048 + ra*32 + swa];
        }
        #pragma unroll
        for (int nt=0; nt<4; nt++){
            int rb = w*64 + nt*16 + fr;
            int swb = (quad ^ ((rb>>1)&3)) << 3;
            bf0[nt] = *(const short8*)&Ws0[bb*8192 + rb*32 + swb];
            bf1[nt] = *(const short8*)&Ws1[bb*8192 + rb*32 + swb];
        }
        #pragma unroll
        for (int mt=0; mt<4; mt++)
            #pragma unroll
            for (int nt=0; nt<4; nt++){
                acc[mt][nt] = __builtin_amdgcn_mfma_f32_16x16x32_bf16(
                    af0[mt], bf0[nt], acc[mt][nt], 0, 0, 0);
                acc[mt][nt] = __builtin_amdgcn_mfma_f32_16x16x32_bf16(
                    af1[mt], bf1[nt], acc[mt][nt], 0, 0, 0);
            }
    };

    const int nst = K >> 6;
    STAGE(0, 0);
    if (nst > 1) STAGE(1, 64);
    int b = 0;
    for (int ts = 0; ts < nst; ++ts){
        if (ts + 1 < nst) asm volatile("s_waitcnt vmcnt(10)" ::: "memory");
        else              asm volatile("s_waitcnt vmcnt(0)"  ::: "memory");
        __builtin_amdgcn_s_barrier();
        COMPUTE(b);
        __builtin_amdgcn_s_barrier();
        if (ts + 2 < nst) STAGE(b, (ts+2) << 6);
        b ^= 1;
    }

    // ---- epilogue: v = acc + bias + residual ----
    float bb4[4], gg[4], be[4];
    #pragma unroll
    for (int nt=0; nt<4; nt++){
        int col = w*64 + nt*16 + fr;
        bb4[nt] = bias[col]; gg[nt] = gam[col]; be[nt] = bet[col];
    }
    #pragma unroll
    for (int mt=0; mt<4; mt++){
        #pragma unroll
        for (int r=0; r<4; r++){
            size_t row = row0 + mb + mt*16 + quad*4 + r;
            #pragma unroll
            for (int nt=0; nt<4; nt++)
                acc[mt][nt][r] += bb4[nt] + bf2f(h[row*HD + w*64 + nt*16 + fr]);
        }
    }
    __syncthreads();
    float* red  = (float*)smem;            // 256 f32
    float* red2 = (float*)(smem + 512);    // 256 f32
    float ps[4][4];
    #pragma unroll
    for (int mt=0; mt<4; mt++)
        #pragma unroll
        for (int r=0; r<4; r++){
            float s = acc[mt][0][r] + acc[mt][1][r] + acc[mt][2][r] + acc[mt][3][r];
            s += __shfl_xor(s,1,64); s += __shfl_xor(s,2,64);
            s += __shfl_xor(s,4,64); s += __shfl_xor(s,8,64);
            ps[mt][r] = s;
        }
    if (fr == 0){
        #pragma unroll
        for (int mt=0; mt<4; mt++)
            #pragma unroll
            for (int r=0; r<4; r++)
                red[w*64 + mt*16 + quad*4 + r] = ps[mt][r];
    }
    __syncthreads();
    float mean[4][4];
    #pragma unroll
    for (int mt=0; mt<4; mt++)
        #pragma unroll
        for (int r=0; r<4; r++){
            int rl = mt*16 + quad*4 + r;
            mean[mt][r] = (red[rl] + red[64+rl] + red[128+rl] + red[192+rl]) * (1.f/256.f);
            float s = 0.f;
            #pragma unroll
            for (int nt=0; nt<4; nt++){ float d = acc[mt][nt][r] - mean[mt][r]; s += d*d; }
            s += __shfl_xor(s,1,64); s += __shfl_xor(s,2,64);
            s += __shfl_xor(s,4,64); s += __shfl_xor(s,8,64);
            ps[mt][r] = s;
        }
    if (fr == 0){
        #pragma unroll
        for (int mt=0; mt<4; mt++)
            #pragma unroll
            for (int r=0; r<4; r++)
                red2[w*64 + mt*16 + quad*4 + r] = ps[mt][r];
    }
    __syncthreads();
    // ---- normalize -> LDS tile -> coalesced stores ----
    u16* Ct = smem + 8192;                 // 64x256 u16
    #pragma unroll
    for (int mt=0; mt<4; mt++)
        #pragma unroll
        for (int r=0; r<4; r++){
            int rl = mt*16 + quad*4 + r;
            float inv = rsqrtf((red2[rl] + red2[64+rl] + red2[128+rl] + red2[192+rl])
                               * (1.f/256.f) + EPSV);
            float o0 = (acc[mt][0][r] - mean[mt][r]) * inv * gg[0] + be[0];
            float o1 = (acc[mt][1][r] - mean[mt][r]) * inv * gg[1] + be[1];
            float o2 = (acc[mt][2][r] - mean[mt][r]) * inv * gg[2] + be[2];
            float o3 = (acc[mt][3][r] - mean[mt][r]) * inv * gg[3] + be[3];
            u32 p01 = cvtpk(o0, o1), p23 = cvtpk(o2, o3);
            Ct[rl*256 + w*64 +  0 + fr] = (u16)p01;
            Ct[rl*256 + w*64 + 16 + fr] = (u16)(p01 >> 16);
            Ct[rl*256 + w*64 + 32 + fr] = (u16)p23;
            Ct[rl*256 + w*64 + 48 + fr] = (u16)(p23 >> 16);
        }
    __syncthreads();
    #pragma unroll
    for (int it=0; it<8; ++it){
        int row = it*8 + (t>>5);
        int seg = t & 31;
        *(short8*)&h[(row0 + mb + row)*HD + seg*8] = *(const short8*)&Ct[row*256 + seg*8];
    }
}

// ---------------- MFMA attention, 8-wave occupancy variant + T5 setprio (r12 proven) ----
#define KS_STR 40
#define VT_STR 136
__global__ __launch_bounds__(512)
void k_attn(u16* __restrict__ qkv)
{
    __shared__ u16 smem[24576];   // 48 KB. stage: Ks 2x4480 @0 | Vt 2x4352 @8960 (dead after prefetch)
                                  // strips: Ph [0,12288) | Pv [12288,24576), per (head,wsgrp) offsets
    int t = threadIdx.x;
    int w = t >> 6, lane = t & 63;
    int fr = lane & 15, quad = lane >> 4;
    int p = t >> 8, t2 = t & 255;          // staging half (one per head)
    u16* Ks = smem + p*4480;
    u16* Vt = smem + 8960 + p*4352;

    {
        int gp = blockIdx.x*2 + p;
        size_t base = (size_t)(gp >> 3)*LSEQ*768 + (gp & 7)*32;
        for (int idx = t2; idx < 1792; idx += 256){
            int key = idx >> 4, d2 = (idx & 15) << 1;
            u32 kv = (key < LSEQ) ? *(const u32*)&qkv[base + (size_t)key*768 + 256 + d2] : 0u;
            *(u32*)&Ks[key*KS_STR + d2] = kv;
        }
        // key-major V transpose staging: lanes stride-1 in key -> conflict-free writes
        for (int idx = t2; idx < 2048; idx += 256){
            int key = idx & 127, d2 = (idx >> 7) << 1;
            u32 vv = (key < LSEQ) ? *(const u32*)&qkv[base + (size_t)key*768 + 512 + d2] : 0u;
            Vt[ d2   *VT_STR + key] = (u16)(vv & 0xffffu);
            Vt[(d2+1)*VT_STR + key] = (u16)(vv >> 16);
        }
    }
    __syncthreads();

    int hp = w >> 2;              // head within block (0,1)
    int ws = w & 3;               // strip group (0..3)
    int gp = blockIdx.x*2 + hp;
    size_t base = (size_t)(gp >> 3)*LSEQ*768 + (gp & 7)*32;
    u16* Ksw = smem + hp*4480;
    u16* Vtw = smem + 8960 + hp*4352;

    short8 kf[7];
    #pragma unroll
    for (int nt=0; nt<7; nt++)
        kf[nt] = *(const short8*)&Ksw[(nt*16 + fr)*KS_STR + quad*8];
    short8 vfr[4][2];
    #pragma unroll
    for (int ks=0; ks<4; ks++)
        #pragma unroll
        for (int nt=0; nt<2; nt++)
            vfr[ks][nt] = *(const short8*)&Vtw[(nt*16 + fr)*VT_STR + ks*32 + quad*8];

    // strip groups: {6}, {0,5}, {1,4}, {2,3} — 7 S-units each
    int smask = (ws==0) ? 0x40 : (ws==1) ? 0x21 : (ws==2) ? 0x12 : 0x0C;
    // prefetch q fragments for this wave's strips (before any output store can alias)
    short8 qfs[7];
    #pragma unroll
    for (int st=0; st<7; ++st){
        if (!((smask >> st) & 1)) continue;
        int q = st*16 + fr;
        short8 z = {};
        qfs[st] = (q < LSEQ) ? *(const short8*)&qkv[base + (size_t)q*768 + quad*8] : z;
    }
    __syncthreads();   // all waves done reading Ks/Vt before Ph/Pv overlay reuse

    // per-(head, strip-group) P buffers: sizes 2048/1536/1536/1024 u16
    int pref = ws ? (1536*ws + 512) : 0;
    u16* Ph = smem + hp*6144 + pref;            // [0, 12288)
    u16* Pv = smem + 12288 + hp*6144 + pref;    // [12288, 24576)

    const float cs = 0.17677669529663687f * 1.4426950408889634f;  // (1/sqrt32)*log2(e)
    #pragma unroll
    for (int st = 0; st < 7; ++st){
        if (!((smask >> st) & 1)) continue;
        const int ntile = (st == 6) ? 7 : (st + 1);
        const int nks   = (st == 6) ? 4 : (st/2 + 1);
        f32x4 S[7];
        __builtin_amdgcn_s_setprio(1);          // T5: favor this wave's QK^T MFMA cluster
        #pragma unroll
        for (int nt=0; nt<7; nt++){
            if (nt >= ntile) continue;
            f32x4 z = {};
            S[nt] = __builtin_amdgcn_mfma_f32_16x16x32_bf16(qfs[st], kf[nt], z, 0,0,0);
        }
        __builtin_amdgcn_s_setprio(0);
        // scale (in log2 domain); mask ONLY the last tile (full tiles causal-valid)
        float mx[4] = {-1e30f,-1e30f,-1e30f,-1e30f};
        #pragma unroll
        for (int nt=0;nt<7;nt++){
            if (nt >= ntile) continue;
            #pragma unroll
            for (int r=0;r<4;r++){
                float s = S[nt][r]*cs;
                if (nt == ntile-1){
                    int qr = st*16 + quad*4 + r;
                    int jmax = (qr < TT) ? qr : (LSEQ-1);
                    s = ((nt*16 + fr) <= jmax) ? s : -1e30f;
                }
                S[nt][r] = s;
                mx[r] = fmaxf(mx[r], s);
            }
        }
        #pragma unroll
        for (int r=0;r<4;r++){
            #pragma unroll
            for (int m=1;m<16;m<<=1) mx[r] = fmaxf(mx[r], __shfl_xor(mx[r], m, 64));
        }
        float l4[4] = {0.f,0.f,0.f,0.f};
        #pragma unroll
        for (int r=0;r<4;r++){
            #pragma unroll
            for (int nt=0;nt<7;nt++){
                if (nt >= ntile) continue;
                float pv = EXP2F(S[nt][r] - mx[r]);
                S[nt][r] = pv;
                l4[r] += pv;
            }
        }
        #pragma unroll
        for (int r=0;r<4;r++){
            #pragma unroll
            for (int m=1;m<16;m<<=1) l4[r] += __shfl_xor(l4[r], m, 64);
        }
        // WAR fence: this wave's previous strip's Ph/Pv reads must complete (buffers private)
        asm volatile("s_waitcnt lgkmcnt(0)" ::: "memory");
        // write P_hi + P_lo via packed cvt; panel layout [ks][16 rows][32 k], XOR swizzle
        #pragma unroll
        for (int nt=0;nt<7;nt++){
            if (nt >= ntile) continue;
            u32 h01 = cvtpk(S[nt][0], S[nt][1]);
            u32 h23 = cvtpk(S[nt][2], S[nt][3]);
            float l0 = S[nt][0] - lo16(h01);
            float l1 = S[nt][1] - hi16(h01);
            float l2 = S[nt][2] - lo16(h23);
            float l3 = S[nt][3] - hi16(h23);
            u32 g01 = cvtpk(l0, l1);
            u32 g23 = cvtpk(l2, l3);
            u16 hv[4] = {(u16)h01, (u16)(h01>>16), (u16)h23, (u16)(h23>>16)};
            u16 lv[4] = {(u16)g01, (u16)(g01>>16), (u16)g23, (u16)(g23>>16)};
            #pragma unroll
            for (int r=0;r<4;r++){
                int row = quad*4 + r;
                int a = (nt>>1)*512 + row*32 + ((((nt&1)<<4) + fr) ^ (((row>>1)&3)<<3));
                Ph[a] = hv[r];
                Pv[a] = lv[r];
            }
        }
        if (ntile*16 < nks*32){
            #pragma unroll
            for (int r=0;r<4;r++){
                int row = quad*4 + r;
                int a = (ntile>>1)*512 + row*32 + ((((ntile&1)<<4) + fr) ^ (((row>>1)&3)<<3));
                Ph[a] = 0;
                Pv[a] = 0;
            }
        }
        asm volatile("s_waitcnt lgkmcnt(0)" ::: "memory");
        f32x4 D[2] = {};
        __builtin_amdgcn_s_setprio(1);          // T5: favor PV MFMA cluster
        #pragma unroll
        for (int ks=0; ks<4; ks++){
            if (ks >= nks) continue;
            int a = ks*512 + fr*32 + ((quad ^ ((fr>>1)&3)) << 3);
            short8 ph = *(const short8*)&Ph[a];
            short8 pl = *(const short8*)&Pv[a];
            #pragma unroll
            for (int nt=0; nt<2; nt++){
                D[nt] = __builtin_amdgcn_mfma_f32_16x16x32_bf16(ph, vfr[ks][nt], D[nt], 0,0,0);
                D[nt] = __builtin_amdgcn_mfma_f32_16x16x32_bf16(pl, vfr[ks][nt], D[nt], 0,0,0);
            }
        }
        __builtin_amdgcn_s_setprio(0);
        #pragma unroll
        for (int r=0;r<4;r++){
            int qr = st*16 + quad*4 + r;
            if (qr < LSEQ){
                float inv = 1.f / l4[r];
                u32 o = cvtpk(D[0][r]*inv, D[1][r]*inv);
                qkv[base + (size_t)qr*768 +      fr] = (u16)o;
                qkv[base + (size_t)qr*768 + 16 + fr] = (u16)(o >> 16);
            }
        }
        // no trailing drain: next strip's WAR fence orders LDS; global rows disjoint
    }
}

// ---------------- mixprop prep ----------------
__global__ __launch_bounds__(256)
void k_mixprep(const u16* __restrict__ h, const float* __restrict__ a,
               u16* __restrict__ amid)
{
    int n = blockIdx.x >> 2, tt = blockIdx.x & 3;
    __shared__ float xs[256][17], h1s[256][17], h2s[256][17];
    __shared__ float as[16][17];
    int t = threadIdx.x;
    as[t>>4][t&15] = a[t];
    for (int idx=t; idx<4096; idx+=256){
        int w = idx >> 8, hc = idx & 255;
        xs[hc][w] = bf2f(h[((size_t)(n*16 + w)*LSEQ + TT + tt)*HD + hc]);
    }
    __syncthreads();
    for (int idx=t; idx<4096; idx+=256){
        int v = idx & 15, hc = idx >> 4;
        float acc = 0.f;
        #pragma unroll
        for (int w=0;w<16;w++) acc += as[v][w]*xs[hc][w];
        h1s[hc][v] = acc;
    }
    __syncthreads();
    for (int idx=t; idx<4096; idx+=256){
        int v = idx & 15, hc = idx >> 4;
        float acc = 0.f;
        #pragma unroll
        for (int w=0;w<16;w++) acc += as[v][w]*h1s[hc][w];
        h2s[hc][v] = acc;
    }
    __syncthreads();
    int hc = t;
    #pragma unroll
    for (int w=0;w<16;w++){
        size_t row = (size_t)((n*16 + w)*4 + tt);
        amid[row*768 +       hc] = f2bf(xs[hc][w]);
        amid[row*768 + 256 + hc] = f2bf(h1s[hc][w]);
        amid[row*768 + 512 + hc] = f2bf(h2s[hc][w]);
    }
}

// ---------------- head ----------------
__global__ __launch_bounds__(256)
void k_z(const u16* __restrict__ h, u16* __restrict__ z)
{
    int bid = blockIdx.x, t = threadIdx.x;     // bid = n*16+c
    #pragma unroll
    for (int tc=0;tc<4;tc++)
        z[((size_t)bid*4 + tc)*HD + t] = f2bf(tanhf(bf2f(h[((size_t)bid*LSEQ + TT + tc)*HD + t])));
}

__global__ __launch_bounds__(256)
void k_head1p(const u16* __restrict__ z, const float* __restrict__ Wd1,
              float* __restrict__ d1p)
{
    __shared__ float zch[64][137];
    __shared__ float wt[16][137];
    int t = threadIdx.x;
    int col = t & 15, rgrp = t >> 4;
    int ob = blockIdx.x * 16;
    int kb = blockIdx.y;
    float acc[4] = {0.f,0.f,0.f,0.f};
    for (int kc=0; kc<1024; kc+=128){
        int base_k = kb*1024 + kc;
        #pragma unroll
        for (int jj=0; jj<16; jj++){
            int idx = t + jj*256;
            int n = idx >> 6, k2 = (idx & 63) << 1;
            u32 r = *(const u32*)&z[(size_t)n*16384 + base_k + k2];
            zch[n][k2] = lo16(r); zch[n][k2+1] = hi16(r);
        }
        #pragma unroll
        for (int jj=0; jj<2; jj++){
            int idx = t + jj*256;
            int r = idx >> 5, k4 = (idx & 31) << 2;
            float4 w4 = *(const float4*)&Wd1[(size_t)(ob + r)*16384 + base_k + k4];
            wt[r][k4] = w4.x; wt[r][k4+1] = w4.y; wt[r][k4+2] = w4.z; wt[r][k4+3] = w4.w;
        }
        __syncthreads();
        for (int k=0;k<128;k++){
            float wv = wt[col][k];
            #pragma unroll
            for (int u=0;u<4;u++) acc[u] += zch[rgrp + 16*u][k]*wv;
        }
        __syncthreads();
    }
    #pragma unroll
    for (int u=0;u<4;u++)
        d1p[(size_t)(kb*64 + rgrp + 16*u)*HD + ob + col] = acc[u];
}

__global__ __launch_bounds__(256)
void k_headf(const float* __restrict__ d1p, const float* __restrict__ bd1,
             const float* __restrict__ Wd2, const float* __restrict__ bd2,
             float* __restrict__ out)
{
    __shared__ float red[4];
    int n = blockIdx.x, c = threadIdx.x;
    float s = 0.f;
    #pragma unroll
    for (int kb=0; kb<16; kb++) s += d1p[(size_t)(kb*64 + n)*HD + c];
    float xx = s + bd1[c];
    float ge = 0.5f*xx*(1.f + erff(xx*0.70710678118654752f));
    float p = ge * Wd2[c];
    #pragma unroll
    for (int m=1;m<64;m<<=1) p += __shfl_xor(p, m, 64);
    if ((c & 63) == 0) red[c >> 6] = p;
    __syncthreads();
    if (c == 0) out[n] = red[0]+red[1]+red[2]+red[3] + bd2[0];
}

// ---------------- launch ----------------
extern "C" void kernel_launch(void* const* d_in, const int* in_sizes, int n_in,
                              void* d_out, int out_size, void* d_ws, size_t ws_size,
                              hipStream_t stream)
{
    const float* x    = (const float*)d_in[0];
    const float* Wfc  = (const float*)d_in[3];
    const float* bfc  = (const float*)d_in[4];
    const float* cls  = (const float*)d_in[5];
    const float* pos  = (const float*)d_in[6];
    const float* emb1 = (const float*)d_in[7];
    const float* emb2 = (const float*)d_in[8];
    const float* Wl1  = (const float*)d_in[9];
    const float* bl1  = (const float*)d_in[10];
    const float* Wl2  = (const float*)d_in[11];
    const float* bl2  = (const float*)d_in[12];
    const float* Wqkv = (const float*)d_in[13];
    const float* bqkv = (const float*)d_in[14];
    const float* Wo   = (const float*)d_in[15];
    const float* bo   = (const float*)d_in[16];
    const float* W1   = (const float*)d_in[17];
    const float* b1   = (const float*)d_in[18];
    const float* W2   = (const float*)d_in[19];
    const float* b2   = (const float*)d_in[20];
    const float* ln1g = (const float*)d_in[21];
    const float* ln1b = (const float*)d_in[22];
    const float* ln2g = (const float*)d_in[23];
    const float* ln2b = (const float*)d_in[24];
    const float* Wmlp = (const float*)d_in[25];
    const float* bmlp = (const float*)d_in[26];
    const float* Wd1  = (const float*)d_in[27];
    const float* bd1  = (const float*)d_in[28];
    const float* Wd2  = (const float*)d_in[29];
    const float* bd2  = (const float*)d_in[30];

    // dynamic chunk selection (2048 B/token)
    int NCH = 8;
    {
        const size_t fixed = 63145088 + (1<<20);
        if      (fixed + (size_t)MTOK    *2048 <= ws_size) NCH = 1;
        else if (fixed + (size_t)(MTOK/2)*2048 <= ws_size) NCH = 2;
        else if (fixed + (size_t)(MTOK/4)*2048 <= ws_size) NCH = 4;
    }
    const int RCH = MTOK / NCH;
    const int SCH = BSEQ / NCH;

    // workspace layout
    u16* h    = (u16*)d_ws;                    // 26,214,400 u16
    u16* buf  = h    + (size_t)MTOK*HD;        // RCH*1024  (qkv / ff1 / mixprop amid)
    u16* wq   = buf  + (size_t)RCH*1024;       //    786,432
    u16* wo   = wq   + (size_t)4*768*256;      //    262,144
    u16* w1   = wo   + (size_t)4*256*256;      //  1,048,576
    u16* w2   = w1   + (size_t)4*1024*256;     //  1,048,576
    u16* wmb  = w2   + (size_t)4*256*1024;     //    589,824
    u16* zb   = wmb  + (size_t)3*256*768;      //  1,048,576
    float* fp = (float*)(zb + (size_t)BSZ*16384);
    float* m1  = fp;
    float* m2  = m1 + CCH*HD;
    float* an  = m2 + CCH*HD;
    float* d1p = an + CCH*CCH;                 // 16*64*256

    // one-time weight prep
    k_cvt<<<512, 256, 0, stream>>>(Wqkv, wq, 4*768*256);
    k_cvt<<<256, 256, 0, stream>>>(Wo,   wo, 4*256*256);
    k_cvt<<<512, 256, 0, stream>>>(W1,   w1, 4*1024*256);
    k_cvt<<<512, 256, 0, stream>>>(W2,   w2, 4*256*1024);
    k_cvt<<<256, 256, 0, stream>>>(Wmlp, wmb, 3*256*768);

    k_embed<<<BSEQ, 256, 0, stream>>>(x, Wfc, bfc, cls, pos, h);
    k_graph_m<<<16, 256, 0, stream>>>(emb1, Wl1, bl1, m1);
    k_graph_m<<<16, 256, 0, stream>>>(emb2, Wl2, bl2, m2);
    k_graph_a<<<1, 256, 0, stream>>>(m1, m2, an);

    for (int l=0; l<NLAY; l++){
        if (l > 0){
            k_mixprep<<<BSZ*NCLS, 256, 0, stream>>>(h, an, buf);
            k_gemmA<<<dim3(256/128, 4096/128), 256, 0, stream>>>(
                buf, 768, wmb + (size_t)(l-1)*256*768, bmlp + (size_t)(l-1)*HD,
                h, HD, 768, 0, 1);
        }

        for (int c=0; c<NCH; c++){
            size_t row0 = (size_t)c * RCH;
            k_gemmA<<<dim3(768/128, RCH/128), 256, 0, stream>>>(
                h + row0*HD, HD, wq + (size_t)l*768*256, bqkv + (size_t)l*768,
                buf, 768, HD, 0, 0);
            k_attn<<<SCH*NHEAD/2, 512, 0, stream>>>(buf);
            // out-proj + residual + LN1 fused (reads q-slot of buf, lda=768)
            k_gemmC<<<RCH/64, 256, 0, stream>>>(
                buf, 768, HD, wo + (size_t)l*256*256, bo + (size_t)l*HD,
                h, ln1g + (size_t)l*HD, ln1b + (size_t)l*HD, row0);
            k_gemmA<<<dim3(1024/128, RCH/128), 256, 0, stream>>>(
                h + row0*HD, HD, w1 + (size_t)l*1024*256, b1 + (size_t)l*1024,
                buf, 1024, HD, 1, 0);
            // FF2 + residual + LN2 fused
            k_gemmC<<<RCH/64, 256, 0, stream>>>(
                buf, 1024, 1024, w2 + (size_t)l*256*1024, b2 + (size_t)l*HD,
                h, ln2g + (size_t)l*HD, ln2b + (size_t)l*HD, row0);
        }
    }

    k_z<<<BSZ*CCH, 256, 0, stream>>>(h, zb);
    k_head1p<<<dim3(16, 16), 256, 0, stream>>>(zb, Wd1, d1p);
    k_headf<<<BSZ, 256, 0, stream>>>(d1p, bd1, Wd2, bd2, (float*)d_out);
}